// Round 1
// baseline (933.289 us; speedup 1.0000x reference)
//
#include <hip/hip_runtime.h>

static constexpr int VD = 16;     // vertex feature dim
static constexpr int SD = 64;     // state dim
static constexpr int ED = 16;     // edge feature dim
static constexpr int KMSG = 2*SD + ED;  // 144
static constexpr int WT_STRIDE = 148;   // 148 % 32 = 20 -> conflict-free b128 phases
static constexpr int RH = 10, RD = 32;
static constexpr int N_ITERS = 3;

__device__ __forceinline__ float dot4f(float4 a, float4 b) {
    return a.x*b.x + a.y*b.y + a.z*b.z + a.w*b.w;
}

__device__ __forceinline__ float sigmoid_f(float x) {
    return 1.f / (1.f + __expf(-x));   // x->+inf: exp(-x)=0 -> 1; x->-inf: exp=inf -> 0. no NaN
}
__device__ __forceinline__ float tanh_f(float x) {
    x = fminf(fmaxf(x, -20.f), 20.f);  // tanh(+-20) == +-1.0f in fp32; avoids inf/inf NaN
    float e = __expf(2.f * x);
    return (e - 1.f) / (e + 1.f);
}

// h[n][j] = node_data[n] @ W_embed[:,j] + b_embed[j]
__global__ void embed_kernel(const float* __restrict__ node_data,
                             const float* __restrict__ W_embed,
                             const float* __restrict__ b_embed,
                             float* __restrict__ h, int n_nodes) {
    int gid = blockIdx.x * blockDim.x + threadIdx.x;
    int n = gid >> 6, j = gid & 63;
    if (n >= n_nodes) return;
    const float* nd = node_data + (size_t)n * VD;   // broadcast reads (same addr across 64 lanes)
    float acc = b_embed[j];
    #pragma unroll
    for (int k = 0; k < VD; ++k) acc += nd[k] * W_embed[k*SD + j];
    h[(size_t)n*SD + j] = acc;
}

__global__ void hist_kernel(const int* __restrict__ edge_dst, int* __restrict__ deg, int n_edges) {
    for (int e = blockIdx.x*blockDim.x + threadIdx.x; e < n_edges; e += gridDim.x*blockDim.x)
        atomicAdd(&deg[edge_dst[e]], 1);
}

// single-block exclusive scan of deg -> row_ptr  (N=20000, chunk=20 per thread)
__global__ __launch_bounds__(1024) void scan_kernel(const int* __restrict__ deg,
                                                    int* __restrict__ row_ptr,
                                                    int n_nodes, int n_edges) {
    __shared__ int s[1024];
    int lid = threadIdx.x;
    int C = (n_nodes + 1023) >> 10;
    int start = lid * C;
    int lsum = 0;
    for (int i = 0; i < C; ++i) { int idx = start + i; if (idx < n_nodes) lsum += deg[idx]; }
    s[lid] = lsum; __syncthreads();
    for (int off = 1; off < 1024; off <<= 1) {
        int v = s[lid];
        int add = (lid >= off) ? s[lid - off] : 0;
        __syncthreads();
        s[lid] = v + add;
        __syncthreads();
    }
    int run = s[lid] - lsum;  // exclusive prefix of this thread's chunk
    for (int i = 0; i < C; ++i) {
        int idx = start + i;
        if (idx < n_nodes) { row_ptr[idx] = run; run += deg[idx]; }
    }
    if (lid == 0) row_ptr[n_nodes] = n_edges;
}

__global__ void fill_kernel(const int* __restrict__ edge_dst, const int* __restrict__ row_ptr,
                            int* __restrict__ fillc, int* __restrict__ eid, int n_edges) {
    for (int e = blockIdx.x*blockDim.x + threadIdx.x; e < n_edges; e += gridDim.x*blockDim.x) {
        int d = edge_dst[e];
        int ofs = atomicAdd(&fillc[d], 1);
        eid[row_ptr[d] + ofs] = e;
    }
}

// Fused message MLP + dst aggregation. One wave per node (wave owns m_acc row -> no atomics).
// W_msg transposed in LDS: Wt[j][k] = W_msg[k][j], stride 148 floats (conflict-free b128).
// h_dst contribution hoisted out of the edge loop (K per edge: 144 -> 80).
// Per-edge inputs (h[src], edge_data) read as same-address float4 broadcasts from global (L2-hot).
__global__ __launch_bounds__(256) void msg_agg_kernel(
        const float* __restrict__ h, const float* __restrict__ edge_data,
        const int* __restrict__ edge_src,
        const float* __restrict__ W_msg, const float* __restrict__ b_msg,
        const int* __restrict__ row_ptr, const int* __restrict__ eid,
        float* __restrict__ m_acc, int n_nodes) {
    __shared__ __align__(16) float Wt[64 * WT_STRIDE];
    for (int idx = threadIdx.x; idx < KMSG*64; idx += blockDim.x) {
        int k = idx >> 6, j = idx & 63;
        Wt[j*WT_STRIDE + k] = W_msg[idx];
    }
    __syncthreads();
    int lane = threadIdx.x & 63;
    int wid = blockIdx.x * (blockDim.x >> 6) + (threadIdx.x >> 6);
    wid = __builtin_amdgcn_readfirstlane(wid);   // force scalar: downstream addrs go SGPR/s_load
    int nw = gridDim.x * (blockDim.x >> 6);
    const float4* Wt4 = (const float4*)(Wt + lane * WT_STRIDE);
    float bj = b_msg[lane];
    for (int n = wid; n < n_nodes; n += nw) {
        int e0 = row_ptr[n], e1 = row_ptr[n + 1];
        if (e0 == e1) continue;                  // zero in-degree: m_acc += 0
        const float4* hn4 = (const float4*)(h + (size_t)n * SD);
        float base = bj;                          // b_msg[j] + h_dst @ W_msg[0:64, j]
        #pragma unroll
        for (int kc = 0; kc < 16; ++kc) base += dot4f(hn4[kc], Wt4[kc]);
        float acc = 0.f;
        for (int i = e0; i < e1; i += 4) {       // 4-edge unroll amortizes LDS W reads
            bool v1 = i+1 < e1, v2 = i+2 < e1, v3 = i+3 < e1;
            int ea = eid[i];
            int eb = v1 ? eid[i+1] : ea;
            int ec = v2 ? eid[i+2] : ea;
            int ed = v3 ? eid[i+3] : ea;
            const float4* s0 = (const float4*)(h + (size_t)edge_src[ea] * SD);
            const float4* s1 = (const float4*)(h + (size_t)edge_src[eb] * SD);
            const float4* s2 = (const float4*)(h + (size_t)edge_src[ec] * SD);
            const float4* s3 = (const float4*)(h + (size_t)edge_src[ed] * SD);
            const float4* d0 = (const float4*)(edge_data + (size_t)ea * ED);
            const float4* d1 = (const float4*)(edge_data + (size_t)eb * ED);
            const float4* d2 = (const float4*)(edge_data + (size_t)ec * ED);
            const float4* d3 = (const float4*)(edge_data + (size_t)ed * ED);
            float m0 = base, m1 = base, m2 = base, m3 = base;
            #pragma unroll 4
            for (int kc = 0; kc < 16; ++kc) {    // h_src part: W rows 64..127
                float4 wv = Wt4[16 + kc];
                m0 += dot4f(s0[kc], wv);
                m1 += dot4f(s1[kc], wv);
                m2 += dot4f(s2[kc], wv);
                m3 += dot4f(s3[kc], wv);
            }
            #pragma unroll
            for (int kc = 0; kc < 4; ++kc) {     // edge_data part: W rows 128..143
                float4 wv = Wt4[32 + kc];
                m0 += dot4f(d0[kc], wv);
                m1 += dot4f(d1[kc], wv);
                m2 += dot4f(d2[kc], wv);
                m3 += dot4f(d3[kc], wv);
            }
            acc += fmaxf(m0, 0.f);
            if (v1) acc += fmaxf(m1, 0.f);
            if (v2) acc += fmaxf(m2, 0.f);
            if (v3) acc += fmaxf(m3, 0.f);
        }
        m_acc[(size_t)n*SD + lane] += acc;
    }
}

// GRU update; wave handles NB=8 nodes so coalesced W_i/W_h column loads (L2-hot) amortize 8x.
// lane j computes gate columns j, 64+j, 128+j of gi and gh.
__global__ __launch_bounds__(256) void gru_kernel(
        float* __restrict__ h, const float* __restrict__ m_acc,
        const float* __restrict__ W_i, const float* __restrict__ b_i,
        const float* __restrict__ W_h, const float* __restrict__ b_h,
        int n_nodes) {
    constexpr int NB = 8;
    int lane = threadIdx.x & 63;
    int wid = blockIdx.x * (blockDim.x >> 6) + (threadIdx.x >> 6);
    wid = __builtin_amdgcn_readfirstlane(wid);
    int nw = gridDim.x * (blockDim.x >> 6);
    for (int g0 = wid * NB; g0 < n_nodes; g0 += nw * NB) {
        const float* mp[NB];
        const float* hp[NB];
        #pragma unroll
        for (int u = 0; u < NB; ++u) {
            int nc = g0 + u; if (nc > n_nodes - 1) nc = n_nodes - 1;  // clamp OOB reads
            mp[u] = m_acc + (size_t)nc * SD;
            hp[u] = h + (size_t)nc * SD;
        }
        float air[NB] = {}, aiz[NB] = {}, ain[NB] = {};
        float ahr[NB] = {}, ahz[NB] = {}, ahn[NB] = {};
        #pragma unroll 4
        for (int k = 0; k < SD; ++k) {
            float wir = W_i[k*192 + lane];
            float wiz = W_i[k*192 + 64 + lane];
            float win = W_i[k*192 + 128 + lane];
            float whr = W_h[k*192 + lane];
            float whz = W_h[k*192 + 64 + lane];
            float whn = W_h[k*192 + 128 + lane];
            #pragma unroll
            for (int u = 0; u < NB; ++u) {
                float mv = mp[u][k];   // broadcast (uniform addr)
                float hv = hp[u][k];
                air[u] += mv*wir; aiz[u] += mv*wiz; ain[u] += mv*win;
                ahr[u] += hv*whr; ahz[u] += hv*whz; ahn[u] += hv*whn;
            }
        }
        float bir = b_i[lane], biz = b_i[64+lane], bin = b_i[128+lane];
        float bhr = b_h[lane], bhz = b_h[64+lane], bhn = b_h[128+lane];
        #pragma unroll
        for (int u = 0; u < NB; ++u) {
            if (g0 + u >= n_nodes) break;
            float r  = sigmoid_f(air[u] + bir + ahr[u] + bhr);
            float z  = sigmoid_f(aiz[u] + biz + ahz[u] + bhz);
            float nn = tanh_f(ain[u] + bin + r * (ahn[u] + bhn));
            float hold = hp[u][lane];
            h[(size_t)(g0+u)*SD + lane] = (1.f - z) * nn + z * hold;
        }
    }
}

// readout: per-node 2-layer MLP, wave shuffle-reduce, 32 atomics per wave
__global__ __launch_bounds__(256) void readout_kernel(
        const float* __restrict__ h, const float* __restrict__ W_r1, const float* __restrict__ b_r1,
        const float* __restrict__ W_r2, const float* __restrict__ b_r2,
        float* __restrict__ out, int n_nodes) {
    float o[RD];
    #pragma unroll
    for (int c = 0; c < RD; ++c) o[c] = 0.f;
    for (int n = blockIdx.x*blockDim.x + threadIdx.x; n < n_nodes; n += gridDim.x*blockDim.x) {
        float t[RH];
        #pragma unroll
        for (int i = 0; i < RH; ++i) t[i] = b_r1[i];
        const float* hn = h + (size_t)n * SD;
        #pragma unroll 4
        for (int k = 0; k < SD; ++k) {
            float hv = hn[k];
            #pragma unroll
            for (int i = 0; i < RH; ++i) t[i] += hv * W_r1[k*RH + i];
        }
        #pragma unroll
        for (int i = 0; i < RH; ++i) t[i] = fmaxf(t[i], 0.f);
        #pragma unroll
        for (int c = 0; c < RD; ++c) {
            float s = b_r2[c];
            #pragma unroll
            for (int i = 0; i < RH; ++i) s += t[i] * W_r2[i*RD + c];
            o[c] += s;
        }
    }
    #pragma unroll
    for (int c = 0; c < RD; ++c) {
        float v = o[c];
        for (int off = 32; off > 0; off >>= 1) v += __shfl_down(v, off);
        if ((threadIdx.x & 63) == 0) atomicAdd(&out[c], v);
    }
}

extern "C" void kernel_launch(void* const* d_in, const int* in_sizes, int n_in,
                              void* d_out, int out_size, void* d_ws, size_t ws_size,
                              hipStream_t stream) {
    const float* node_data = (const float*)d_in[0];
    const float* edge_data = (const float*)d_in[1];
    const int*   edge_src  = (const int*)d_in[2];
    const int*   edge_dst  = (const int*)d_in[3];
    const float* W_embed   = (const float*)d_in[4];
    const float* b_embed   = (const float*)d_in[5];
    const float* W_msg     = (const float*)d_in[6];
    const float* b_msg     = (const float*)d_in[7];
    const float* W_i       = (const float*)d_in[8];
    const float* b_i       = (const float*)d_in[9];
    const float* W_h       = (const float*)d_in[10];
    const float* b_h       = (const float*)d_in[11];
    const float* W_r1      = (const float*)d_in[12];
    const float* b_r1      = (const float*)d_in[13];
    const float* W_r2      = (const float*)d_in[14];
    const float* b_r2      = (const float*)d_in[15];

    int n_nodes = in_sizes[0] / VD;    // 20000
    int n_edges = in_sizes[2];         // 320000

    // workspace layout (256B-aligned slabs), ~11.8 MB total
    char* ws = (char*)d_ws;
    size_t off = 0;
    auto alloc = [&](size_t bytes) {
        void* p = ws + off;
        off = (off + bytes + 255) & ~(size_t)255;
        return p;
    };
    float* h       = (float*)alloc((size_t)n_nodes * SD * sizeof(float));
    float* m_acc   = (float*)alloc((size_t)n_nodes * SD * sizeof(float));
    int*   deg     = (int*)alloc((size_t)n_nodes * sizeof(int));
    int*   row_ptr = (int*)alloc((size_t)(n_nodes + 1) * sizeof(int));
    int*   fillc   = (int*)alloc((size_t)n_nodes * sizeof(int));
    int*   eid     = (int*)alloc((size_t)n_edges * sizeof(int));
    (void)ws_size; (void)n_in;

    // ws/d_out are poisoned 0xAA before every timed call: init everything we accumulate into
    hipMemsetAsync(m_acc, 0, (size_t)n_nodes * SD * sizeof(float), stream);
    hipMemsetAsync(deg,   0, (size_t)n_nodes * sizeof(int), stream);
    hipMemsetAsync(fillc, 0, (size_t)n_nodes * sizeof(int), stream);
    hipMemsetAsync(d_out, 0, (size_t)out_size * sizeof(float), stream);

    embed_kernel<<<(n_nodes*SD + 255)/256, 256, 0, stream>>>(node_data, W_embed, b_embed, h, n_nodes);

    // dst-CSR build (every launch; same work per call)
    hist_kernel<<<(n_edges + 255)/256, 256, 0, stream>>>(edge_dst, deg, n_edges);
    scan_kernel<<<1, 1024, 0, stream>>>(deg, row_ptr, n_nodes, n_edges);
    fill_kernel<<<(n_edges + 255)/256, 256, 0, stream>>>(edge_dst, row_ptr, fillc, eid, n_edges);

    int msg_blocks = (n_nodes + 3) / 4;    // one wave per node, 4 waves/block
    int gru_blocks = (n_nodes + 31) / 32;  // 4 waves/block * 8 nodes/wave
    for (int it = 0; it < N_ITERS; ++it) {
        msg_agg_kernel<<<msg_blocks, 256, 0, stream>>>(h, edge_data, edge_src, W_msg, b_msg,
                                                       row_ptr, eid, m_acc, n_nodes);
        gru_kernel<<<gru_blocks, 256, 0, stream>>>(h, m_acc, W_i, b_i, W_h, b_h, n_nodes);
    }

    readout_kernel<<<(n_nodes + 255)/256, 256, 0, stream>>>(h, W_r1, b_r1, W_r2, b_r2,
                                                            (float*)d_out, n_nodes);
}

// Round 2
// 663.427 us; speedup vs baseline: 1.4068x; 1.4068x over previous
//
#include <hip/hip_runtime.h>

static constexpr int VD = 16;     // vertex feature dim
static constexpr int SD = 64;     // state dim
static constexpr int ED = 16;     // edge feature dim
static constexpr int RH = 10, RD = 32;
static constexpr int N_ITERS = 3;

__device__ __forceinline__ float sigmoid_f(float x) {
    return 1.f / (1.f + __expf(-x));
}
__device__ __forceinline__ float tanh_f(float x) {
    x = fminf(fmaxf(x, -20.f), 20.f);
    float e = __expf(2.f * x);
    return (e - 1.f) / (e + 1.f);
}

// h[n][j] = node_data[n] @ W_embed[:,j] + b_embed[j]
__global__ void embed_kernel(const float* __restrict__ node_data,
                             const float* __restrict__ W_embed,
                             const float* __restrict__ b_embed,
                             float* __restrict__ h, int n_nodes) {
    int gid = blockIdx.x * blockDim.x + threadIdx.x;
    int n = gid >> 6, j = gid & 63;
    if (n >= n_nodes) return;
    const float* nd = node_data + (size_t)n * VD;
    float acc = b_embed[j];
    #pragma unroll
    for (int k = 0; k < VD; ++k) acc += nd[k] * W_embed[k*SD + j];
    h[(size_t)n*SD + j] = acc;
}

__global__ void hist_kernel(const int* __restrict__ edge_dst, int* __restrict__ deg, int n_edges) {
    for (int e = blockIdx.x*blockDim.x + threadIdx.x; e < n_edges; e += gridDim.x*blockDim.x)
        atomicAdd(&deg[edge_dst[e]], 1);
}

// single-block exclusive scan of deg -> row_ptr
__global__ __launch_bounds__(1024) void scan_kernel(const int* __restrict__ deg,
                                                    int* __restrict__ row_ptr,
                                                    int n_nodes, int n_edges) {
    __shared__ int s[1024];
    int lid = threadIdx.x;
    int C = (n_nodes + 1023) >> 10;
    int start = lid * C;
    int lsum = 0;
    for (int i = 0; i < C; ++i) { int idx = start + i; if (idx < n_nodes) lsum += deg[idx]; }
    s[lid] = lsum; __syncthreads();
    for (int off = 1; off < 1024; off <<= 1) {
        int v = s[lid];
        int add = (lid >= off) ? s[lid - off] : 0;
        __syncthreads();
        s[lid] = v + add;
        __syncthreads();
    }
    int run = s[lid] - lsum;
    for (int i = 0; i < C; ++i) {
        int idx = start + i;
        if (idx < n_nodes) { row_ptr[idx] = run; run += deg[idx]; }
    }
    if (lid == 0) row_ptr[n_nodes] = n_edges;
}

__global__ void fill_kernel(const int* __restrict__ edge_dst, const int* __restrict__ row_ptr,
                            int* __restrict__ fillc, int* __restrict__ eid, int n_edges) {
    for (int e = blockIdx.x*blockDim.x + threadIdx.x; e < n_edges; e += gridDim.x*blockDim.x) {
        int d = edge_dst[e];
        int ofs = atomicAdd(&fillc[d], 1);
        eid[row_ptr[d] + ofs] = e;
    }
}

// One-time: permute edge_src and edge_data into CSR (dst-sorted) order -> sequential reads in agg.
__global__ void reorder_kernel(const int* __restrict__ eid, const int* __restrict__ edge_src,
                               const float* __restrict__ edge_data,
                               int* __restrict__ src_csr, float* __restrict__ ed_csr, int n_edges) {
    int i = blockIdx.x*blockDim.x + threadIdx.x;
    if (i >= n_edges) return;
    int e = eid[i];
    src_csr[i] = edge_src[e];
    const float4* s = (const float4*)(edge_data + (size_t)e * ED);
    float4* d = (float4*)(ed_csr + (size_t)i * ED);
    d[0] = s[0]; d[1] = s[1]; d[2] = s[2]; d[3] = s[3];
}

// Per-iter: A[n][c] = h[n]@W_msg[0:64,c] + b_msg[c]  ;  B[n][c] = h[n]@W_msg[64:128,c]
// thread per (n, c) with c in [0,128): c<64 -> A, else B. W is 36 KB L1/L2-hot.
__global__ __launch_bounds__(256) void ab_kernel(
        const float* __restrict__ h, const float* __restrict__ W_msg,
        const float* __restrict__ b_msg,
        float* __restrict__ A, float* __restrict__ B, int n_nodes) {
    int gid = blockIdx.x * blockDim.x + threadIdx.x;
    int n = gid >> 7, c = gid & 127;
    if (n >= n_nodes) return;
    const float4* h4 = (const float4*)(h + (size_t)n * SD);
    bool isA = c < 64;
    int col = isA ? c : c - 64;
    const float* W = W_msg + (isA ? 0 : SD * SD) + col;
    float acc = isA ? b_msg[col] : 0.f;
    #pragma unroll
    for (int k4 = 0; k4 < 16; ++k4) {
        float4 hv = h4[k4];
        int k = k4 * 4;
        acc += hv.x * W[k*64] + hv.y * W[(k+1)*64] + hv.z * W[(k+2)*64] + hv.w * W[(k+3)*64];
    }
    if (isA) A[(size_t)n*SD + col] = acc;
    else     B[(size_t)n*SD + col] = acc;
}

// Fused per-edge message + aggregation, decomposed form:
//   m_acc[n][j] += sum_{edges into n} relu(A[n][j] + B[src][j] + ed_csr[i]@w3col_j)
// Wave per node, lane j owns column j. W3 column in 16 VGPRs (no LDS -> no conflicts).
// B-row reads are coalesced; ed_csr reads sequential; 8-edge chunks for MLP.
__global__ __launch_bounds__(256) void agg_kernel(
        const float* __restrict__ A, const float* __restrict__ B,
        const float* __restrict__ ed_csr, const int* __restrict__ src_csr,
        const float* __restrict__ W_msg,
        const int* __restrict__ row_ptr,
        float* __restrict__ m_acc, int n_nodes) {
    int lane = threadIdx.x & 63;
    int wid = blockIdx.x * (blockDim.x >> 6) + (threadIdx.x >> 6);
    wid = __builtin_amdgcn_readfirstlane(wid);
    int nw = gridDim.x * (blockDim.x >> 6);
    float w3[16];
    #pragma unroll
    for (int t = 0; t < 16; ++t) w3[t] = W_msg[(2*SD + t) * SD + lane];  // coalesced
    for (int n = wid; n < n_nodes; n += nw) {
        int e0 = row_ptr[n], e1 = row_ptr[n + 1];
        if (e0 == e1) continue;
        float a = A[(size_t)n*SD + lane];
        float acc = 0.f;
        for (int i = e0; i < e1; i += 8) {
            int srcs[8];
            #pragma unroll
            for (int t = 0; t < 8; ++t) {
                int idx = i + t; if (idx >= e1) idx = e1 - 1;
                srcs[t] = __builtin_amdgcn_readfirstlane(src_csr[idx]);
            }
            float bv[8];
            #pragma unroll
            for (int t = 0; t < 8; ++t) bv[t] = B[(size_t)srcs[t]*SD + lane];
            float cv[8];
            #pragma unroll
            for (int t = 0; t < 8; ++t) {
                int idx = i + t; if (idx >= e1) idx = e1 - 1;
                const float4* e4 = (const float4*)(ed_csr + (size_t)idx * ED);
                float4 x0 = e4[0], x1 = e4[1], x2 = e4[2], x3 = e4[3];
                cv[t] = x0.x*w3[0]  + x0.y*w3[1]  + x0.z*w3[2]  + x0.w*w3[3]
                      + x1.x*w3[4]  + x1.y*w3[5]  + x1.z*w3[6]  + x1.w*w3[7]
                      + x2.x*w3[8]  + x2.y*w3[9]  + x2.z*w3[10] + x2.w*w3[11]
                      + x3.x*w3[12] + x3.y*w3[13] + x3.z*w3[14] + x3.w*w3[15];
            }
            int cnt = e1 - i;
            #pragma unroll
            for (int t = 0; t < 8; ++t)
                if (t < cnt) acc += fmaxf(a + bv[t] + cv[t], 0.f);
        }
        m_acc[(size_t)n*SD + lane] += acc;
    }
}

// GRU update; wave handles NB=8 nodes; float4 broadcast loads of m/h rows.
__global__ __launch_bounds__(256) void gru_kernel(
        float* __restrict__ h, const float* __restrict__ m_acc,
        const float* __restrict__ W_i, const float* __restrict__ b_i,
        const float* __restrict__ W_h, const float* __restrict__ b_h,
        int n_nodes) {
    constexpr int NB = 8;
    int lane = threadIdx.x & 63;
    int wid = blockIdx.x * (blockDim.x >> 6) + (threadIdx.x >> 6);
    wid = __builtin_amdgcn_readfirstlane(wid);
    int nw = gridDim.x * (blockDim.x >> 6);
    for (int g0 = wid * NB; g0 < n_nodes; g0 += nw * NB) {
        const float4* mp4[NB];
        const float4* hp4[NB];
        #pragma unroll
        for (int u = 0; u < NB; ++u) {
            int nc = g0 + u; if (nc > n_nodes - 1) nc = n_nodes - 1;
            mp4[u] = (const float4*)(m_acc + (size_t)nc * SD);
            hp4[u] = (const float4*)(h + (size_t)nc * SD);
        }
        float air[NB] = {}, aiz[NB] = {}, ain[NB] = {};
        float ahr[NB] = {}, ahz[NB] = {}, ahn[NB] = {};
        #pragma unroll 4
        for (int k4 = 0; k4 < 16; ++k4) {
            int k = k4 * 4;
            float wi0[4], wi1[4], wi2[4], wh0[4], wh1[4], wh2[4];
            #pragma unroll
            for (int d = 0; d < 4; ++d) {
                wi0[d] = W_i[(k+d)*192 + lane];
                wi1[d] = W_i[(k+d)*192 + 64 + lane];
                wi2[d] = W_i[(k+d)*192 + 128 + lane];
                wh0[d] = W_h[(k+d)*192 + lane];
                wh1[d] = W_h[(k+d)*192 + 64 + lane];
                wh2[d] = W_h[(k+d)*192 + 128 + lane];
            }
            #pragma unroll
            for (int u = 0; u < NB; ++u) {
                float4 m4 = mp4[u][k4];
                float4 h4 = hp4[u][k4];
                air[u] += m4.x*wi0[0] + m4.y*wi0[1] + m4.z*wi0[2] + m4.w*wi0[3];
                aiz[u] += m4.x*wi1[0] + m4.y*wi1[1] + m4.z*wi1[2] + m4.w*wi1[3];
                ain[u] += m4.x*wi2[0] + m4.y*wi2[1] + m4.z*wi2[2] + m4.w*wi2[3];
                ahr[u] += h4.x*wh0[0] + h4.y*wh0[1] + h4.z*wh0[2] + h4.w*wh0[3];
                ahz[u] += h4.x*wh1[0] + h4.y*wh1[1] + h4.z*wh1[2] + h4.w*wh1[3];
                ahn[u] += h4.x*wh2[0] + h4.y*wh2[1] + h4.z*wh2[2] + h4.w*wh2[3];
            }
        }
        float bir = b_i[lane], biz = b_i[64+lane], bin = b_i[128+lane];
        float bhr = b_h[lane], bhz = b_h[64+lane], bhn = b_h[128+lane];
        #pragma unroll
        for (int u = 0; u < NB; ++u) {
            if (g0 + u >= n_nodes) break;
            float r  = sigmoid_f(air[u] + bir + ahr[u] + bhr);
            float z  = sigmoid_f(aiz[u] + biz + ahz[u] + bhz);
            float nn = tanh_f(ain[u] + bin + r * (ahn[u] + bhn));
            float hold = ((const float*)hp4[u])[lane];
            h[(size_t)(g0+u)*SD + lane] = (1.f - z) * nn + z * hold;
        }
    }
}

// readout: per-node 2-layer MLP, wave shuffle-reduce, 32 atomics per wave
__global__ __launch_bounds__(256) void readout_kernel(
        const float* __restrict__ h, const float* __restrict__ W_r1, const float* __restrict__ b_r1,
        const float* __restrict__ W_r2, const float* __restrict__ b_r2,
        float* __restrict__ out, int n_nodes) {
    float o[RD];
    #pragma unroll
    for (int c = 0; c < RD; ++c) o[c] = 0.f;
    for (int n = blockIdx.x*blockDim.x + threadIdx.x; n < n_nodes; n += gridDim.x*blockDim.x) {
        float t[RH];
        #pragma unroll
        for (int i = 0; i < RH; ++i) t[i] = b_r1[i];
        const float* hn = h + (size_t)n * SD;
        #pragma unroll 4
        for (int k = 0; k < SD; ++k) {
            float hv = hn[k];
            #pragma unroll
            for (int i = 0; i < RH; ++i) t[i] += hv * W_r1[k*RH + i];
        }
        #pragma unroll
        for (int i = 0; i < RH; ++i) t[i] = fmaxf(t[i], 0.f);
        #pragma unroll
        for (int c = 0; c < RD; ++c) {
            float s = b_r2[c];
            #pragma unroll
            for (int i = 0; i < RH; ++i) s += t[i] * W_r2[i*RD + c];
            o[c] += s;
        }
    }
    #pragma unroll
    for (int c = 0; c < RD; ++c) {
        float v = o[c];
        for (int off = 32; off > 0; off >>= 1) v += __shfl_down(v, off);
        if ((threadIdx.x & 63) == 0) atomicAdd(&out[c], v);
    }
}

extern "C" void kernel_launch(void* const* d_in, const int* in_sizes, int n_in,
                              void* d_out, int out_size, void* d_ws, size_t ws_size,
                              hipStream_t stream) {
    const float* node_data = (const float*)d_in[0];
    const float* edge_data = (const float*)d_in[1];
    const int*   edge_src  = (const int*)d_in[2];
    const int*   edge_dst  = (const int*)d_in[3];
    const float* W_embed   = (const float*)d_in[4];
    const float* b_embed   = (const float*)d_in[5];
    const float* W_msg     = (const float*)d_in[6];
    const float* b_msg     = (const float*)d_in[7];
    const float* W_i       = (const float*)d_in[8];
    const float* b_i       = (const float*)d_in[9];
    const float* W_h       = (const float*)d_in[10];
    const float* b_h       = (const float*)d_in[11];
    const float* W_r1      = (const float*)d_in[12];
    const float* b_r1      = (const float*)d_in[13];
    const float* W_r2      = (const float*)d_in[14];
    const float* b_r2      = (const float*)d_in[15];

    int n_nodes = in_sizes[0] / VD;    // 20000
    int n_edges = in_sizes[2];         // 320000

    // workspace layout (256B-aligned slabs), ~44 MB total
    char* ws = (char*)d_ws;
    size_t off = 0;
    auto alloc = [&](size_t bytes) {
        void* p = ws + off;
        off = (off + bytes + 255) & ~(size_t)255;
        return p;
    };
    float* h       = (float*)alloc((size_t)n_nodes * SD * sizeof(float));
    float* m_acc   = (float*)alloc((size_t)n_nodes * SD * sizeof(float));
    float* A       = (float*)alloc((size_t)n_nodes * SD * sizeof(float));
    float* B       = (float*)alloc((size_t)n_nodes * SD * sizeof(float));
    float* ed_csr  = (float*)alloc((size_t)n_edges * ED * sizeof(float));
    int*   src_csr = (int*)alloc((size_t)n_edges * sizeof(int));
    int*   deg     = (int*)alloc((size_t)n_nodes * sizeof(int));
    int*   row_ptr = (int*)alloc((size_t)(n_nodes + 1) * sizeof(int));
    int*   fillc   = (int*)alloc((size_t)n_nodes * sizeof(int));
    int*   eid     = (int*)alloc((size_t)n_edges * sizeof(int));
    (void)ws_size; (void)n_in;

    hipMemsetAsync(m_acc, 0, (size_t)n_nodes * SD * sizeof(float), stream);
    hipMemsetAsync(deg,   0, (size_t)n_nodes * sizeof(int), stream);
    hipMemsetAsync(fillc, 0, (size_t)n_nodes * sizeof(int), stream);
    hipMemsetAsync(d_out, 0, (size_t)out_size * sizeof(float), stream);

    embed_kernel<<<(n_nodes*SD + 255)/256, 256, 0, stream>>>(node_data, W_embed, b_embed, h, n_nodes);

    // dst-CSR build + one-time permutation of per-edge inputs into CSR order
    hist_kernel<<<(n_edges + 255)/256, 256, 0, stream>>>(edge_dst, deg, n_edges);
    scan_kernel<<<1, 1024, 0, stream>>>(deg, row_ptr, n_nodes, n_edges);
    fill_kernel<<<(n_edges + 255)/256, 256, 0, stream>>>(edge_dst, row_ptr, fillc, eid, n_edges);
    reorder_kernel<<<(n_edges + 255)/256, 256, 0, stream>>>(eid, edge_src, edge_data, src_csr, ed_csr, n_edges);

    int ab_blocks  = (n_nodes*128 + 255)/256;
    int agg_blocks = (n_nodes + 3) / 4;    // wave per node, 4 waves/block
    int gru_blocks = (n_nodes + 31) / 32;  // 4 waves/block * 8 nodes/wave
    for (int it = 0; it < N_ITERS; ++it) {
        ab_kernel<<<ab_blocks, 256, 0, stream>>>(h, W_msg, b_msg, A, B, n_nodes);
        agg_kernel<<<agg_blocks, 256, 0, stream>>>(A, B, ed_csr, src_csr, W_msg, row_ptr, m_acc, n_nodes);
        gru_kernel<<<gru_blocks, 256, 0, stream>>>(h, m_acc, W_i, b_i, W_h, b_h, n_nodes);
    }

    readout_kernel<<<(n_nodes + 255)/256, 256, 0, stream>>>(h, W_r1, b_r1, W_r2, b_r2,
                                                            (float*)d_out, n_nodes);
}

// Round 3
// 567.657 us; speedup vs baseline: 1.6441x; 1.1687x over previous
//
#include <hip/hip_runtime.h>

static constexpr int VD = 16;     // vertex feature dim
static constexpr int SD = 64;     // state dim
static constexpr int ED = 16;     // edge feature dim
static constexpr int RH = 10, RD = 32;
static constexpr int N_ITERS = 3;

__device__ __forceinline__ float sigmoid_f(float x) {
    return 1.f / (1.f + __expf(-x));
}
__device__ __forceinline__ float tanh_f(float x) {
    x = fminf(fmaxf(x, -20.f), 20.f);
    float e = __expf(2.f * x);
    return (e - 1.f) / (e + 1.f);
}

// h[n][j] = node_data[n] @ W_embed[:,j] + b_embed[j]
__global__ void embed_kernel(const float* __restrict__ node_data,
                             const float* __restrict__ W_embed,
                             const float* __restrict__ b_embed,
                             float* __restrict__ h, int n_nodes) {
    int gid = blockIdx.x * blockDim.x + threadIdx.x;
    int n = gid >> 6, j = gid & 63;
    if (n >= n_nodes) return;
    const float* nd = node_data + (size_t)n * VD;
    float acc = b_embed[j];
    #pragma unroll
    for (int k = 0; k < VD; ++k) acc += nd[k] * W_embed[k*SD + j];
    h[(size_t)n*SD + j] = acc;
}

__global__ void hist_kernel(const int* __restrict__ edge_dst, int* __restrict__ deg, int n_edges) {
    for (int e = blockIdx.x*blockDim.x + threadIdx.x; e < n_edges; e += gridDim.x*blockDim.x)
        atomicAdd(&deg[edge_dst[e]], 1);
}

// single-block exclusive scan of deg -> row_ptr
__global__ __launch_bounds__(1024) void scan_kernel(const int* __restrict__ deg,
                                                    int* __restrict__ row_ptr,
                                                    int n_nodes, int n_edges) {
    __shared__ int s[1024];
    int lid = threadIdx.x;
    int C = (n_nodes + 1023) >> 10;
    int start = lid * C;
    int lsum = 0;
    for (int i = 0; i < C; ++i) { int idx = start + i; if (idx < n_nodes) lsum += deg[idx]; }
    s[lid] = lsum; __syncthreads();
    for (int off = 1; off < 1024; off <<= 1) {
        int v = s[lid];
        int add = (lid >= off) ? s[lid - off] : 0;
        __syncthreads();
        s[lid] = v + add;
        __syncthreads();
    }
    int run = s[lid] - lsum;
    for (int i = 0; i < C; ++i) {
        int idx = start + i;
        if (idx < n_nodes) { row_ptr[idx] = run; run += deg[idx]; }
    }
    if (lid == 0) row_ptr[n_nodes] = n_edges;
}

__global__ void fill_kernel(const int* __restrict__ edge_dst, const int* __restrict__ row_ptr,
                            int* __restrict__ fillc, int* __restrict__ eid, int n_edges) {
    for (int e = blockIdx.x*blockDim.x + threadIdx.x; e < n_edges; e += gridDim.x*blockDim.x) {
        int d = edge_dst[e];
        int ofs = atomicAdd(&fillc[d], 1);
        eid[row_ptr[d] + ofs] = e;
    }
}

// One-time: permute edge_src and edge_data into CSR (dst-sorted) order.
__global__ void reorder_kernel(const int* __restrict__ eid, const int* __restrict__ edge_src,
                               const float* __restrict__ edge_data,
                               int* __restrict__ src_csr, float* __restrict__ ed_csr, int n_edges) {
    int i = blockIdx.x*blockDim.x + threadIdx.x;
    if (i >= n_edges) return;
    int e = eid[i];
    src_csr[i] = edge_src[e];
    const float4* s = (const float4*)(edge_data + (size_t)e * ED);
    float4* d = (float4*)(ed_csr + (size_t)i * ED);
    d[0] = s[0]; d[1] = s[1]; d[2] = s[2]; d[3] = s[3];
}

// Per-iter: A[n][c] = h[n]@W_msg[0:64,c] + b_msg[c]  ;  B[n][c] = h[n]@W_msg[64:128,c]
__global__ __launch_bounds__(256) void ab_kernel(
        const float* __restrict__ h, const float* __restrict__ W_msg,
        const float* __restrict__ b_msg,
        float* __restrict__ A, float* __restrict__ B, int n_nodes) {
    int gid = blockIdx.x * blockDim.x + threadIdx.x;
    int n = gid >> 7, c = gid & 127;
    if (n >= n_nodes) return;
    const float4* h4 = (const float4*)(h + (size_t)n * SD);
    bool isA = c < 64;
    int col = isA ? c : c - 64;
    const float* W = W_msg + (isA ? 0 : SD * SD) + col;
    float acc = isA ? b_msg[col] : 0.f;
    #pragma unroll
    for (int k4 = 0; k4 < 16; ++k4) {
        float4 hv = h4[k4];
        int k = k4 * 4;
        acc += hv.x * W[k*64] + hv.y * W[(k+1)*64] + hv.z * W[(k+2)*64] + hv.w * W[(k+3)*64];
    }
    if (isA) A[(size_t)n*SD + col] = acc;
    else     B[(size_t)n*SD + col] = acc;
}

// Fused per-edge message + aggregation:
//   m_acc[n][j] += sum_{edges into n} relu(A[n][j] + B[src][j] + ed_csr[i]@w3col_j)
// Wave per node, lane j owns column j. Src indices: ONE coalesced 8-wide load +
// readlane broadcasts (replaces 8 serialized scalar loads).
__global__ __launch_bounds__(256) void agg_kernel(
        const float* __restrict__ A, const float* __restrict__ B,
        const float* __restrict__ ed_csr, const int* __restrict__ src_csr,
        const float* __restrict__ W_msg,
        const int* __restrict__ row_ptr,
        float* __restrict__ m_acc, int n_nodes) {
    int lane = threadIdx.x & 63;
    int wid = blockIdx.x * (blockDim.x >> 6) + (threadIdx.x >> 6);
    wid = __builtin_amdgcn_readfirstlane(wid);
    int nw = gridDim.x * (blockDim.x >> 6);
    float w3[16];
    #pragma unroll
    for (int t = 0; t < 16; ++t) w3[t] = W_msg[(2*SD + t) * SD + lane];  // coalesced
    for (int n = wid; n < n_nodes; n += nw) {
        int e0 = row_ptr[n], e1 = row_ptr[n + 1];
        if (e0 == e1) continue;
        float a = A[(size_t)n*SD + lane];
        float acc = 0.f;
        for (int i = e0; i < e1; i += 8) {
            int idx8 = i + (lane & 7); if (idx8 >= e1) idx8 = e1 - 1;
            int sv = src_csr[idx8];                  // one 32B-segment broadcast load
            int srcs[8];
            #pragma unroll
            for (int t = 0; t < 8; ++t) srcs[t] = __builtin_amdgcn_readlane(sv, t);
            float bv[8];
            #pragma unroll
            for (int t = 0; t < 8; ++t) bv[t] = B[(size_t)srcs[t]*SD + lane];  // coalesced rows
            float cv[8];
            #pragma unroll
            for (int t = 0; t < 8; ++t) {
                int idx = i + t; if (idx >= e1) idx = e1 - 1;
                const float4* e4 = (const float4*)(ed_csr + (size_t)idx * ED);
                float4 x0 = e4[0], x1 = e4[1], x2 = e4[2], x3 = e4[3];
                cv[t] = x0.x*w3[0]  + x0.y*w3[1]  + x0.z*w3[2]  + x0.w*w3[3]
                      + x1.x*w3[4]  + x1.y*w3[5]  + x1.z*w3[6]  + x1.w*w3[7]
                      + x2.x*w3[8]  + x2.y*w3[9]  + x2.z*w3[10] + x2.w*w3[11]
                      + x3.x*w3[12] + x3.y*w3[13] + x3.z*w3[14] + x3.w*w3[15];
            }
            int cnt = e1 - i;
            #pragma unroll
            for (int t = 0; t < 8; ++t)
                if (t < cnt) acc += fmaxf(a + bv[t] + cv[t], 0.f);
        }
        m_acc[(size_t)n*SD + lane] += acc;
    }
}

// GRU update; wave handles NB=8 nodes; float4 broadcast loads of m/h rows.
__global__ __launch_bounds__(256) void gru_kernel(
        float* __restrict__ h, const float* __restrict__ m_acc,
        const float* __restrict__ W_i, const float* __restrict__ b_i,
        const float* __restrict__ W_h, const float* __restrict__ b_h,
        int n_nodes) {
    constexpr int NB = 8;
    int lane = threadIdx.x & 63;
    int wid = blockIdx.x * (blockDim.x >> 6) + (threadIdx.x >> 6);
    wid = __builtin_amdgcn_readfirstlane(wid);
    int nw = gridDim.x * (blockDim.x >> 6);
    for (int g0 = wid * NB; g0 < n_nodes; g0 += nw * NB) {
        const float4* mp4[NB];
        const float4* hp4[NB];
        #pragma unroll
        for (int u = 0; u < NB; ++u) {
            int nc = g0 + u; if (nc > n_nodes - 1) nc = n_nodes - 1;
            mp4[u] = (const float4*)(m_acc + (size_t)nc * SD);
            hp4[u] = (const float4*)(h + (size_t)nc * SD);
        }
        float air[NB] = {}, aiz[NB] = {}, ain[NB] = {};
        float ahr[NB] = {}, ahz[NB] = {}, ahn[NB] = {};
        #pragma unroll 4
        for (int k4 = 0; k4 < 16; ++k4) {
            int k = k4 * 4;
            float wi0[4], wi1[4], wi2[4], wh0[4], wh1[4], wh2[4];
            #pragma unroll
            for (int d = 0; d < 4; ++d) {
                wi0[d] = W_i[(k+d)*192 + lane];
                wi1[d] = W_i[(k+d)*192 + 64 + lane];
                wi2[d] = W_i[(k+d)*192 + 128 + lane];
                wh0[d] = W_h[(k+d)*192 + lane];
                wh1[d] = W_h[(k+d)*192 + 64 + lane];
                wh2[d] = W_h[(k+d)*192 + 128 + lane];
            }
            #pragma unroll
            for (int u = 0; u < NB; ++u) {
                float4 m4 = mp4[u][k4];
                float4 h4 = hp4[u][k4];
                air[u] += m4.x*wi0[0] + m4.y*wi0[1] + m4.z*wi0[2] + m4.w*wi0[3];
                aiz[u] += m4.x*wi1[0] + m4.y*wi1[1] + m4.z*wi1[2] + m4.w*wi1[3];
                ain[u] += m4.x*wi2[0] + m4.y*wi2[1] + m4.z*wi2[2] + m4.w*wi2[3];
                ahr[u] += h4.x*wh0[0] + h4.y*wh0[1] + h4.z*wh0[2] + h4.w*wh0[3];
                ahz[u] += h4.x*wh1[0] + h4.y*wh1[1] + h4.z*wh1[2] + h4.w*wh1[3];
                ahn[u] += h4.x*wh2[0] + h4.y*wh2[1] + h4.z*wh2[2] + h4.w*wh2[3];
            }
        }
        float bir = b_i[lane], biz = b_i[64+lane], bin = b_i[128+lane];
        float bhr = b_h[lane], bhz = b_h[64+lane], bhn = b_h[128+lane];
        #pragma unroll
        for (int u = 0; u < NB; ++u) {
            if (g0 + u >= n_nodes) break;
            float r  = sigmoid_f(air[u] + bir + ahr[u] + bhr);
            float z  = sigmoid_f(aiz[u] + biz + ahz[u] + bhz);
            float nn = tanh_f(ain[u] + bin + r * (ahn[u] + bhn));
            float hold = ((const float*)hp4[u])[lane];
            h[(size_t)(g0+u)*SD + lane] = (1.f - z) * nn + z * hold;
        }
    }
}

// Readout v2: block stages a 128-node h tile into LDS (coalesced float4 loads,
// pad stride 65 -> conflict-free per-lane row reads), then thread-per-node MLP
// from LDS, wave shuffle-reduce, 32 atomics per block.
__global__ __launch_bounds__(128) void readout_kernel(
        const float* __restrict__ h, const float* __restrict__ W_r1, const float* __restrict__ b_r1,
        const float* __restrict__ W_r2, const float* __restrict__ b_r2,
        float* __restrict__ out, int n_nodes) {
    __shared__ float hs[128 * 65];
    __shared__ float osum[2 * RD];
    int tile0 = blockIdx.x * 128;
    // stage 128 rows x 64 cols: 2048 float4s over 128 threads = 16 each, coalesced
    #pragma unroll
    for (int j = 0; j < 16; ++j) {
        int f = threadIdx.x + j * 128;
        int row = f >> 4, c4 = (f & 15) * 4;
        int n = tile0 + row;
        float4 v = make_float4(0.f, 0.f, 0.f, 0.f);
        if (n < n_nodes) v = ((const float4*)(h + (size_t)n * SD))[f & 15];
        hs[row*65 + c4 + 0] = v.x;
        hs[row*65 + c4 + 1] = v.y;
        hs[row*65 + c4 + 2] = v.z;
        hs[row*65 + c4 + 3] = v.w;
    }
    __syncthreads();
    float o[RD];
    #pragma unroll
    for (int c = 0; c < RD; ++c) o[c] = 0.f;
    int n = tile0 + threadIdx.x;
    if (n < n_nodes) {
        const float* hr = hs + threadIdx.x * 65;   // bank (t + k) % 32: conflict-free
        float t[RH];
        #pragma unroll
        for (int i = 0; i < RH; ++i) t[i] = b_r1[i];
        #pragma unroll 4
        for (int k = 0; k < SD; ++k) {
            float hv = hr[k];
            #pragma unroll
            for (int i = 0; i < RH; ++i) t[i] += hv * W_r1[k*RH + i];  // uniform -> s_load
        }
        #pragma unroll
        for (int i = 0; i < RH; ++i) t[i] = fmaxf(t[i], 0.f);
        #pragma unroll
        for (int c = 0; c < RD; ++c) {
            float s = b_r2[c];
            #pragma unroll
            for (int i = 0; i < RH; ++i) s += t[i] * W_r2[i*RD + c];
            o[c] = s;
        }
    }
    int lane = threadIdx.x & 63;
    int wv = threadIdx.x >> 6;
    #pragma unroll
    for (int c = 0; c < RD; ++c) {
        float v = o[c];
        for (int off = 32; off > 0; off >>= 1) v += __shfl_down(v, off);
        if (lane == 0) osum[wv*RD + c] = v;
    }
    __syncthreads();
    if (threadIdx.x < RD) atomicAdd(&out[threadIdx.x], osum[threadIdx.x] + osum[RD + threadIdx.x]);
}

extern "C" void kernel_launch(void* const* d_in, const int* in_sizes, int n_in,
                              void* d_out, int out_size, void* d_ws, size_t ws_size,
                              hipStream_t stream) {
    const float* node_data = (const float*)d_in[0];
    const float* edge_data = (const float*)d_in[1];
    const int*   edge_src  = (const int*)d_in[2];
    const int*   edge_dst  = (const int*)d_in[3];
    const float* W_embed   = (const float*)d_in[4];
    const float* b_embed   = (const float*)d_in[5];
    const float* W_msg     = (const float*)d_in[6];
    const float* b_msg     = (const float*)d_in[7];
    const float* W_i       = (const float*)d_in[8];
    const float* b_i       = (const float*)d_in[9];
    const float* W_h       = (const float*)d_in[10];
    const float* b_h       = (const float*)d_in[11];
    const float* W_r1      = (const float*)d_in[12];
    const float* b_r1      = (const float*)d_in[13];
    const float* W_r2      = (const float*)d_in[14];
    const float* b_r2      = (const float*)d_in[15];

    int n_nodes = in_sizes[0] / VD;    // 20000
    int n_edges = in_sizes[2];         // 320000

    char* ws = (char*)d_ws;
    size_t off = 0;
    auto alloc = [&](size_t bytes) {
        void* p = ws + off;
        off = (off + bytes + 255) & ~(size_t)255;
        return p;
    };
    float* h       = (float*)alloc((size_t)n_nodes * SD * sizeof(float));
    float* m_acc   = (float*)alloc((size_t)n_nodes * SD * sizeof(float));
    float* A       = (float*)alloc((size_t)n_nodes * SD * sizeof(float));
    float* B       = (float*)alloc((size_t)n_nodes * SD * sizeof(float));
    float* ed_csr  = (float*)alloc((size_t)n_edges * ED * sizeof(float));
    int*   src_csr = (int*)alloc((size_t)n_edges * sizeof(int));
    int*   deg     = (int*)alloc((size_t)n_nodes * sizeof(int));
    int*   row_ptr = (int*)alloc((size_t)(n_nodes + 1) * sizeof(int));
    int*   fillc   = (int*)alloc((size_t)n_nodes * sizeof(int));
    int*   eid     = (int*)alloc((size_t)n_edges * sizeof(int));
    (void)ws_size; (void)n_in;

    hipMemsetAsync(m_acc, 0, (size_t)n_nodes * SD * sizeof(float), stream);
    hipMemsetAsync(deg,   0, (size_t)n_nodes * sizeof(int), stream);
    hipMemsetAsync(fillc, 0, (size_t)n_nodes * sizeof(int), stream);
    hipMemsetAsync(d_out, 0, (size_t)out_size * sizeof(float), stream);

    embed_kernel<<<(n_nodes*SD + 255)/256, 256, 0, stream>>>(node_data, W_embed, b_embed, h, n_nodes);

    hist_kernel<<<(n_edges + 255)/256, 256, 0, stream>>>(edge_dst, deg, n_edges);
    scan_kernel<<<1, 1024, 0, stream>>>(deg, row_ptr, n_nodes, n_edges);
    fill_kernel<<<(n_edges + 255)/256, 256, 0, stream>>>(edge_dst, row_ptr, fillc, eid, n_edges);
    reorder_kernel<<<(n_edges + 255)/256, 256, 0, stream>>>(eid, edge_src, edge_data, src_csr, ed_csr, n_edges);

    int ab_blocks  = (n_nodes*128 + 255)/256;
    int agg_blocks = (n_nodes + 3) / 4;
    int gru_blocks = (n_nodes + 31) / 32;
    for (int it = 0; it < N_ITERS; ++it) {
        ab_kernel<<<ab_blocks, 256, 0, stream>>>(h, W_msg, b_msg, A, B, n_nodes);
        agg_kernel<<<agg_blocks, 256, 0, stream>>>(A, B, ed_csr, src_csr, W_msg, row_ptr, m_acc, n_nodes);
        gru_kernel<<<gru_blocks, 256, 0, stream>>>(h, m_acc, W_i, b_i, W_h, b_h, n_nodes);
    }

    readout_kernel<<<(n_nodes + 127)/128, 128, 0, stream>>>(h, W_r1, b_r1, W_r2, b_r2,
                                                            (float*)d_out, n_nodes);
}

// Round 4
// 482.879 us; speedup vs baseline: 1.9328x; 1.1756x over previous
//
#include <hip/hip_runtime.h>

static constexpr int VD = 16;     // vertex feature dim
static constexpr int SD = 64;     // state dim
static constexpr int ED = 16;     // edge feature dim
static constexpr int RH = 10, RD = 32;
static constexpr int N_ITERS = 3;

__device__ __forceinline__ float sigmoid_f(float x) {
    return 1.f / (1.f + __expf(-x));
}
__device__ __forceinline__ float tanh_f(float x) {
    x = fminf(fmaxf(x, -20.f), 20.f);
    float e = __expf(2.f * x);
    return (e - 1.f) / (e + 1.f);
}
__device__ __forceinline__ unsigned short f2bf(float x) {   // round-to-nearest-even
    unsigned u = __float_as_uint(x);
    unsigned r = (u + 0x7FFFu + ((u >> 16) & 1u)) >> 16;
    return (unsigned short)r;
}
__device__ __forceinline__ float bf2f(unsigned short s) {
    return __uint_as_float(((unsigned)s) << 16);
}

// h[n][j] = node_data[n] @ W_embed[:,j] + b_embed[j]
__global__ void embed_kernel(const float* __restrict__ node_data,
                             const float* __restrict__ W_embed,
                             const float* __restrict__ b_embed,
                             float* __restrict__ h, int n_nodes) {
    int gid = blockIdx.x * blockDim.x + threadIdx.x;
    int n = gid >> 6, j = gid & 63;
    if (n >= n_nodes) return;
    const float* nd = node_data + (size_t)n * VD;
    float acc = b_embed[j];
    #pragma unroll
    for (int k = 0; k < VD; ++k) acc += nd[k] * W_embed[k*SD + j];
    h[(size_t)n*SD + j] = acc;
}

__global__ void hist_kernel(const int* __restrict__ edge_dst, int* __restrict__ deg, int n_edges) {
    for (int e = blockIdx.x*blockDim.x + threadIdx.x; e < n_edges; e += gridDim.x*blockDim.x)
        atomicAdd(&deg[edge_dst[e]], 1);
}

// single-block exclusive scan of deg -> row_ptr
__global__ __launch_bounds__(1024) void scan_kernel(const int* __restrict__ deg,
                                                    int* __restrict__ row_ptr,
                                                    int n_nodes, int n_edges) {
    __shared__ int s[1024];
    int lid = threadIdx.x;
    int C = (n_nodes + 1023) >> 10;
    int start = lid * C;
    int lsum = 0;
    for (int i = 0; i < C; ++i) { int idx = start + i; if (idx < n_nodes) lsum += deg[idx]; }
    s[lid] = lsum; __syncthreads();
    for (int off = 1; off < 1024; off <<= 1) {
        int v = s[lid];
        int add = (lid >= off) ? s[lid - off] : 0;
        __syncthreads();
        s[lid] = v + add;
        __syncthreads();
    }
    int run = s[lid] - lsum;
    for (int i = 0; i < C; ++i) {
        int idx = start + i;
        if (idx < n_nodes) { row_ptr[idx] = run; run += deg[idx]; }
    }
    if (lid == 0) row_ptr[n_nodes] = n_edges;
}

__global__ void fill_kernel(const int* __restrict__ edge_dst, const int* __restrict__ row_ptr,
                            int* __restrict__ fillc, int* __restrict__ eid, int n_edges) {
    for (int e = blockIdx.x*blockDim.x + threadIdx.x; e < n_edges; e += gridDim.x*blockDim.x) {
        int d = edge_dst[e];
        int ofs = atomicAdd(&fillc[d], 1);
        eid[row_ptr[d] + ofs] = e;
    }
}

// Once: src_csr[i] = edge_src[eid[i]]; C[i][j] = edge_data[eid[i]] @ W3[:,j]  (bf16).
// Wave handles a 64-edge chunk: coalesced eid/src loads, then per-edge broadcast
// edge_data reads (independent, all in flight) + 16-FMA dot with W3 col in VGPRs.
__global__ __launch_bounds__(256) void edgeconst_kernel(
        const int* __restrict__ eid, const int* __restrict__ edge_src,
        const float* __restrict__ edge_data, const float* __restrict__ W_msg,
        int* __restrict__ src_csr, unsigned short* __restrict__ C, int n_edges) {
    int lane = threadIdx.x & 63;
    int wid = blockIdx.x * (blockDim.x >> 6) + (threadIdx.x >> 6);
    wid = __builtin_amdgcn_readfirstlane(wid);
    int nw = gridDim.x * (blockDim.x >> 6);
    float w3[16];
    #pragma unroll
    for (int t = 0; t < 16; ++t) w3[t] = W_msg[(2*SD + t) * SD + lane];
    for (int i0 = wid * 64; i0 < n_edges; i0 += nw * 64) {
        int idx = i0 + lane;
        bool valid = idx < n_edges;
        int e = valid ? eid[idx] : 0;                    // coalesced
        if (valid) src_csr[idx] = edge_src[e];           // gather + coalesced store
        int cnt = n_edges - i0; if (cnt > 64) cnt = 64;
        #pragma unroll 8
        for (int t = 0; t < 64; ++t) {
            if (t >= cnt) break;
            int et = __builtin_amdgcn_readlane(e, t);
            const float4* e4 = (const float4*)(edge_data + (size_t)et * ED);
            float4 x0 = e4[0], x1 = e4[1], x2 = e4[2], x3 = e4[3];
            float cv = x0.x*w3[0]  + x0.y*w3[1]  + x0.z*w3[2]  + x0.w*w3[3]
                     + x1.x*w3[4]  + x1.y*w3[5]  + x1.z*w3[6]  + x1.w*w3[7]
                     + x2.x*w3[8]  + x2.y*w3[9]  + x2.z*w3[10] + x2.w*w3[11]
                     + x3.x*w3[12] + x3.y*w3[13] + x3.z*w3[14] + x3.w*w3[15];
            C[(size_t)(i0 + t) * SD + lane] = f2bf(cv);  // coalesced 128B/edge
        }
    }
}

// Per-iter fused pass over h: [A | B | GH] = h @ [W1 | W2 | W_h] (+biases).
// Block = 320 threads (col c), node-tile of 8 so weight reads amortize 8x.
__global__ __launch_bounds__(320) void abgh_kernel(
        const float* __restrict__ h,
        const float* __restrict__ W_msg, const float* __restrict__ b_msg,
        const float* __restrict__ W_h,   const float* __restrict__ b_h,
        float* __restrict__ A, float* __restrict__ B, float* __restrict__ GH,
        int n_nodes) {
    int c = threadIdx.x;                 // 0..319, wave-uniform branch below
    int n0 = blockIdx.x * 8;
    const float* Wcol; int stride; float bias; float* Out; int ostride; int ocol;
    if (c < 64)       { Wcol = W_msg + c;              stride = 64;  bias = b_msg[c];     Out = A;  ostride = 64;  ocol = c; }
    else if (c < 128) { Wcol = W_msg + SD*SD + (c-64); stride = 64;  bias = 0.f;          Out = B;  ostride = 64;  ocol = c - 64; }
    else              { Wcol = W_h + (c-128);          stride = 192; bias = b_h[c-128];   Out = GH; ostride = 192; ocol = c - 128; }
    int nn = n_nodes - n0; if (nn > 8) nn = 8; if (nn <= 0) return;
    const float4* h4[8];
    #pragma unroll
    for (int u = 0; u < 8; ++u) h4[u] = (const float4*)(h + (size_t)(n0 + (u < nn ? u : 0)) * SD);
    float acc[8];
    #pragma unroll
    for (int u = 0; u < 8; ++u) acc[u] = bias;
    #pragma unroll 4
    for (int k4 = 0; k4 < 16; ++k4) {
        int k = k4 * 4;
        float w0 = Wcol[(k+0)*stride], w1 = Wcol[(k+1)*stride];
        float w2 = Wcol[(k+2)*stride], w3 = Wcol[(k+3)*stride];
        #pragma unroll
        for (int u = 0; u < 8; ++u) {
            float4 hv = h4[u][k4];    // broadcast (block-uniform address)
            acc[u] += hv.x*w0 + hv.y*w1 + hv.z*w2 + hv.w*w3;
        }
    }
    for (int u = 0; u < nn; ++u)
        Out[(size_t)(n0 + u) * ostride + ocol] = acc[u];   // coalesced
}

// Fused aggregation: m_acc[n][j] (=|+=) sum_edges relu(A[n][j] + B[src][j] + C[i][j])
// Wave per node; all loads coalesced; FIRST variant writes (kills the m_acc memset).
template<int FIRST>
__global__ __launch_bounds__(256) void agg_kernel(
        const float* __restrict__ A, const float* __restrict__ B,
        const unsigned short* __restrict__ C, const int* __restrict__ src_csr,
        const int* __restrict__ row_ptr,
        float* __restrict__ m_acc, int n_nodes) {
    int lane = threadIdx.x & 63;
    int wid = blockIdx.x * (blockDim.x >> 6) + (threadIdx.x >> 6);
    wid = __builtin_amdgcn_readfirstlane(wid);
    int nw = gridDim.x * (blockDim.x >> 6);
    for (int n = wid; n < n_nodes; n += nw) {
        int e0 = row_ptr[n], e1 = row_ptr[n + 1];
        float acc = 0.f;
        if (e0 < e1) {
            float a = A[(size_t)n*SD + lane];
            for (int i = e0; i < e1; i += 8) {
                int idx8 = i + (lane & 7); if (idx8 >= e1) idx8 = e1 - 1;
                int sv = src_csr[idx8];
                int srcs[8];
                #pragma unroll
                for (int t = 0; t < 8; ++t) srcs[t] = __builtin_amdgcn_readlane(sv, t);
                float bv[8], cv[8];
                #pragma unroll
                for (int t = 0; t < 8; ++t) bv[t] = B[(size_t)srcs[t]*SD + lane];
                #pragma unroll
                for (int t = 0; t < 8; ++t) {
                    int idx = i + t; if (idx >= e1) idx = e1 - 1;
                    cv[t] = bf2f(C[(size_t)idx*SD + lane]);
                }
                int cnt = e1 - i;
                #pragma unroll
                for (int t = 0; t < 8; ++t)
                    if (t < cnt) acc += fmaxf(a + bv[t] + cv[t], 0.f);
            }
        }
        if (FIRST) m_acc[(size_t)n*SD + lane] = acc;
        else       m_acc[(size_t)n*SD + lane] += acc;
    }
}

// GRU: gi = m_acc@W_i + b_i (computed here, NB=4 nodes/wave -> 5000 waves of TLP);
// gh comes precomputed from abgh. Gates + h update fused.
__global__ __launch_bounds__(256) void gru_kernel(
        float* __restrict__ h, const float* __restrict__ m_acc,
        const float* __restrict__ GH,
        const float* __restrict__ W_i, const float* __restrict__ b_i,
        int n_nodes) {
    constexpr int NB = 4;
    int lane = threadIdx.x & 63;
    int wid = blockIdx.x * (blockDim.x >> 6) + (threadIdx.x >> 6);
    wid = __builtin_amdgcn_readfirstlane(wid);
    int g0 = wid * NB;
    if (g0 >= n_nodes) return;
    int nn = n_nodes - g0; if (nn > NB) nn = NB;
    const float4* mp4[NB];
    #pragma unroll
    for (int u = 0; u < NB; ++u)
        mp4[u] = (const float4*)(m_acc + (size_t)(g0 + (u < nn ? u : 0)) * SD);
    float air[NB] = {}, aiz[NB] = {}, ain[NB] = {};
    #pragma unroll 4
    for (int k4 = 0; k4 < 16; ++k4) {
        int k = k4 * 4;
        float wi0[4], wi1[4], wi2[4];
        #pragma unroll
        for (int d = 0; d < 4; ++d) {
            wi0[d] = W_i[(k+d)*192 + lane];
            wi1[d] = W_i[(k+d)*192 + 64 + lane];
            wi2[d] = W_i[(k+d)*192 + 128 + lane];
        }
        #pragma unroll
        for (int u = 0; u < NB; ++u) {
            float4 m4 = mp4[u][k4];
            air[u] += m4.x*wi0[0] + m4.y*wi0[1] + m4.z*wi0[2] + m4.w*wi0[3];
            aiz[u] += m4.x*wi1[0] + m4.y*wi1[1] + m4.z*wi1[2] + m4.w*wi1[3];
            ain[u] += m4.x*wi2[0] + m4.y*wi2[1] + m4.z*wi2[2] + m4.w*wi2[3];
        }
    }
    float bir = b_i[lane], biz = b_i[64+lane], bin = b_i[128+lane];
    #pragma unroll
    for (int u = 0; u < NB; ++u) {
        if (u >= nn) break;
        int n = g0 + u;
        float ghr = GH[(size_t)n*192 + lane];
        float ghz = GH[(size_t)n*192 + 64 + lane];
        float ghn = GH[(size_t)n*192 + 128 + lane];
        float r  = sigmoid_f(air[u] + bir + ghr);
        float z  = sigmoid_f(aiz[u] + biz + ghz);
        float nv = tanh_f(ain[u] + bin + r * ghn);
        float hold = h[(size_t)n*SD + lane];
        h[(size_t)n*SD + lane] = (1.f - z) * nv + z * hold;
    }
}

// Readout: LDS-staged 128-node tile, thread-per-node MLP, shuffle-reduce, 32 atomics/block.
__global__ __launch_bounds__(128) void readout_kernel(
        const float* __restrict__ h, const float* __restrict__ W_r1, const float* __restrict__ b_r1,
        const float* __restrict__ W_r2, const float* __restrict__ b_r2,
        float* __restrict__ out, int n_nodes) {
    __shared__ float hs[128 * 65];
    __shared__ float osum[2 * RD];
    int tile0 = blockIdx.x * 128;
    #pragma unroll
    for (int j = 0; j < 16; ++j) {
        int f = threadIdx.x + j * 128;
        int row = f >> 4, c4 = (f & 15) * 4;
        int n = tile0 + row;
        float4 v = make_float4(0.f, 0.f, 0.f, 0.f);
        if (n < n_nodes) v = ((const float4*)(h + (size_t)n * SD))[f & 15];
        hs[row*65 + c4 + 0] = v.x;
        hs[row*65 + c4 + 1] = v.y;
        hs[row*65 + c4 + 2] = v.z;
        hs[row*65 + c4 + 3] = v.w;
    }
    __syncthreads();
    float o[RD];
    #pragma unroll
    for (int c = 0; c < RD; ++c) o[c] = 0.f;
    int n = tile0 + threadIdx.x;
    if (n < n_nodes) {
        const float* hr = hs + threadIdx.x * 65;
        float t[RH];
        #pragma unroll
        for (int i = 0; i < RH; ++i) t[i] = b_r1[i];
        #pragma unroll 4
        for (int k = 0; k < SD; ++k) {
            float hv = hr[k];
            #pragma unroll
            for (int i = 0; i < RH; ++i) t[i] += hv * W_r1[k*RH + i];
        }
        #pragma unroll
        for (int i = 0; i < RH; ++i) t[i] = fmaxf(t[i], 0.f);
        #pragma unroll
        for (int c = 0; c < RD; ++c) {
            float s = b_r2[c];
            #pragma unroll
            for (int i = 0; i < RH; ++i) s += t[i] * W_r2[i*RD + c];
            o[c] = s;
        }
    }
    int lane = threadIdx.x & 63;
    int wv = threadIdx.x >> 6;
    #pragma unroll
    for (int c = 0; c < RD; ++c) {
        float v = o[c];
        for (int off = 32; off > 0; off >>= 1) v += __shfl_down(v, off);
        if (lane == 0) osum[wv*RD + c] = v;
    }
    __syncthreads();
    if (threadIdx.x < RD) atomicAdd(&out[threadIdx.x], osum[threadIdx.x] + osum[RD + threadIdx.x]);
}

extern "C" void kernel_launch(void* const* d_in, const int* in_sizes, int n_in,
                              void* d_out, int out_size, void* d_ws, size_t ws_size,
                              hipStream_t stream) {
    const float* node_data = (const float*)d_in[0];
    const float* edge_data = (const float*)d_in[1];
    const int*   edge_src  = (const int*)d_in[2];
    const int*   edge_dst  = (const int*)d_in[3];
    const float* W_embed   = (const float*)d_in[4];
    const float* b_embed   = (const float*)d_in[5];
    const float* W_msg     = (const float*)d_in[6];
    const float* b_msg     = (const float*)d_in[7];
    const float* W_i       = (const float*)d_in[8];
    const float* b_i       = (const float*)d_in[9];
    const float* W_h       = (const float*)d_in[10];
    const float* b_h       = (const float*)d_in[11];
    const float* W_r1      = (const float*)d_in[12];
    const float* b_r1      = (const float*)d_in[13];
    const float* W_r2      = (const float*)d_in[14];
    const float* b_r2      = (const float*)d_in[15];

    int n_nodes = in_sizes[0] / VD;    // 20000
    int n_edges = in_sizes[2];         // 320000

    char* ws = (char*)d_ws;
    size_t off = 0;
    auto alloc = [&](size_t bytes) {
        void* p = ws + off;
        off = (off + bytes + 255) & ~(size_t)255;
        return p;
    };
    float* h        = (float*)alloc((size_t)n_nodes * SD * sizeof(float));
    float* m_acc    = (float*)alloc((size_t)n_nodes * SD * sizeof(float));
    float* A        = (float*)alloc((size_t)n_nodes * SD * sizeof(float));
    float* B        = (float*)alloc((size_t)n_nodes * SD * sizeof(float));
    float* GH       = (float*)alloc((size_t)n_nodes * 192 * sizeof(float));
    unsigned short* C = (unsigned short*)alloc((size_t)n_edges * SD * sizeof(unsigned short));
    int*   src_csr  = (int*)alloc((size_t)n_edges * sizeof(int));
    int*   deg      = (int*)alloc((size_t)n_nodes * sizeof(int));
    int*   row_ptr  = (int*)alloc((size_t)(n_nodes + 1) * sizeof(int));
    int*   fillc    = (int*)alloc((size_t)n_nodes * sizeof(int));
    int*   eid      = (int*)alloc((size_t)n_edges * sizeof(int));
    (void)ws_size; (void)n_in;

    hipMemsetAsync(deg,   0, (size_t)n_nodes * sizeof(int), stream);
    hipMemsetAsync(fillc, 0, (size_t)n_nodes * sizeof(int), stream);
    hipMemsetAsync(d_out, 0, (size_t)out_size * sizeof(float), stream);

    embed_kernel<<<(n_nodes*SD + 255)/256, 256, 0, stream>>>(node_data, W_embed, b_embed, h, n_nodes);

    hist_kernel<<<(n_edges + 255)/256, 256, 0, stream>>>(edge_dst, deg, n_edges);
    scan_kernel<<<1, 1024, 0, stream>>>(deg, row_ptr, n_nodes, n_edges);
    fill_kernel<<<(n_edges + 255)/256, 256, 0, stream>>>(edge_dst, row_ptr, fillc, eid, n_edges);
    edgeconst_kernel<<<(n_edges/64 + 3)/4, 256, 0, stream>>>(eid, edge_src, edge_data, W_msg,
                                                             src_csr, C, n_edges);

    int abgh_blocks = (n_nodes + 7) / 8;
    int agg_blocks  = (n_nodes + 3) / 4;
    int gru_blocks  = ((n_nodes + 3) / 4 + 3) / 4;
    for (int it = 0; it < N_ITERS; ++it) {
        abgh_kernel<<<abgh_blocks, 320, 0, stream>>>(h, W_msg, b_msg, W_h, b_h, A, B, GH, n_nodes);
        if (it == 0)
            agg_kernel<1><<<agg_blocks, 256, 0, stream>>>(A, B, C, src_csr, row_ptr, m_acc, n_nodes);
        else
            agg_kernel<0><<<agg_blocks, 256, 0, stream>>>(A, B, C, src_csr, row_ptr, m_acc, n_nodes);
        gru_kernel<<<gru_blocks, 256, 0, stream>>>(h, m_acc, GH, W_i, b_i, n_nodes);
    }

    readout_kernel<<<(n_nodes + 127)/128, 128, 0, stream>>>(h, W_r1, b_r1, W_r2, b_r2,
                                                            (float*)d_out, n_nodes);
}

// Round 5
// 352.561 us; speedup vs baseline: 2.6472x; 1.3696x over previous
//
#include <hip/hip_runtime.h>

static constexpr int VD = 16;     // vertex feature dim
static constexpr int SD = 64;     // state dim
static constexpr int ED = 16;     // edge feature dim
static constexpr int RH = 10, RD = 32;
static constexpr int N_ITERS = 3;

typedef __attribute__((ext_vector_type(8))) short short8;
typedef __attribute__((ext_vector_type(4))) float floatx4;

__device__ __forceinline__ float sigmoid_f(float x) {
    return 1.f / (1.f + __expf(-x));
}
__device__ __forceinline__ float tanh_f(float x) {
    x = fminf(fmaxf(x, -20.f), 20.f);
    float e = __expf(2.f * x);
    return (e - 1.f) / (e + 1.f);
}
__device__ __forceinline__ unsigned short f2bf(float x) {   // round-to-nearest-even
    unsigned u = __float_as_uint(x);
    unsigned r = (u + 0x7FFFu + ((u >> 16) & 1u)) >> 16;
    return (unsigned short)r;
}
__device__ __forceinline__ float bf2f(unsigned short s) {
    return __uint_as_float(((unsigned)s) << 16);
}

// h[n][j] = node_data[n] @ W_embed[:,j] + b_embed[j]; also writes bf16 copy.
__global__ void embed_kernel(const float* __restrict__ node_data,
                             const float* __restrict__ W_embed,
                             const float* __restrict__ b_embed,
                             float* __restrict__ h, unsigned short* __restrict__ hb,
                             int n_nodes) {
    int gid = blockIdx.x * blockDim.x + threadIdx.x;
    int n = gid >> 6, j = gid & 63;
    if (n >= n_nodes) return;
    const float* nd = node_data + (size_t)n * VD;
    float acc = b_embed[j];
    #pragma unroll
    for (int k = 0; k < VD; ++k) acc += nd[k] * W_embed[k*SD + j];
    h[(size_t)n*SD + j] = acc;
    hb[(size_t)n*SD + j] = f2bf(acc);
}

// One-time bf16 weight transposes for MFMA B-operands ([n][k] layout).
__global__ void prep_w_kernel(const float* __restrict__ W_msg,
                              const float* __restrict__ W_i, const float* __restrict__ W_h,
                              unsigned short* __restrict__ WabT, unsigned short* __restrict__ WiT,
                              unsigned short* __restrict__ WhT, unsigned short* __restrict__ W3T) {
    int i = blockIdx.x * blockDim.x + threadIdx.x;
    if (i < 128*64) {                       // WabT[n][k]: n<64 -> W1 col n; else W2 col n-64
        int n = i >> 6, k = i & 63;
        WabT[i] = f2bf(W_msg[((n < 64 ? 0 : 64) + k)*64 + (n & 63)]);
    }
    int j = i - 128*64;
    if (j >= 0 && j < 192*64) {             // WiT/WhT[n][k] = W[k][n]
        int n = j >> 6, k = j & 63;
        WiT[j] = f2bf(W_i[k*192 + n]);
        WhT[j] = f2bf(W_h[k*192 + n]);
    }
    int l = i - 128*64 - 192*64;
    if (l >= 0 && l < 64*32) {              // W3T[n][k], k padded 16->32 with zeros
        int n = l >> 5, k = l & 31;
        W3T[l] = (k < 16) ? f2bf(W_msg[(128+k)*64 + n]) : (unsigned short)0;
    }
}

__global__ void hist_kernel(const int* __restrict__ edge_dst, int* __restrict__ deg, int n_edges) {
    for (int e = blockIdx.x*blockDim.x + threadIdx.x; e < n_edges; e += gridDim.x*blockDim.x)
        atomicAdd(&deg[edge_dst[e]], 1);
}

__global__ __launch_bounds__(1024) void scan_kernel(const int* __restrict__ deg,
                                                    int* __restrict__ row_ptr,
                                                    int n_nodes, int n_edges) {
    __shared__ int s[1024];
    int lid = threadIdx.x;
    int C = (n_nodes + 1023) >> 10;
    int start = lid * C;
    int lsum = 0;
    for (int i = 0; i < C; ++i) { int idx = start + i; if (idx < n_nodes) lsum += deg[idx]; }
    s[lid] = lsum; __syncthreads();
    for (int off = 1; off < 1024; off <<= 1) {
        int v = s[lid];
        int add = (lid >= off) ? s[lid - off] : 0;
        __syncthreads();
        s[lid] = v + add;
        __syncthreads();
    }
    int run = s[lid] - lsum;
    for (int i = 0; i < C; ++i) {
        int idx = start + i;
        if (idx < n_nodes) { row_ptr[idx] = run; run += deg[idx]; }
    }
    if (lid == 0) row_ptr[n_nodes] = n_edges;
}

__global__ void fill_kernel(const int* __restrict__ edge_dst, const int* __restrict__ row_ptr,
                            int* __restrict__ fillc, int* __restrict__ eid, int n_edges) {
    for (int e = blockIdx.x*blockDim.x + threadIdx.x; e < n_edges; e += gridDim.x*blockDim.x) {
        int d = edge_dst[e];
        int ofs = atomicAdd(&fillc[d], 1);
        eid[row_ptr[d] + ofs] = e;
    }
}

// Once: Cb[i][j] = edge_data[eid[i]] @ W3[:,j] (bf16) via K-padded MFMA; also src_csr gather.
// Block's 4 waves share the same 16-edge tile (nt=0..3) -> gathers hit L1.
__global__ __launch_bounds__(256) void edgeconst_kernel(
        const int* __restrict__ eid, const int* __restrict__ edge_src,
        const float* __restrict__ edge_data, const unsigned short* __restrict__ W3T,
        int* __restrict__ src_csr, unsigned short* __restrict__ Cb, int n_edges) {
    int w = blockIdx.x * 4 + (threadIdx.x >> 6);
    int lane = threadIdx.x & 63;
    int et = w >> 2, nt = w & 3;
    int e0 = et * 16;
    if (e0 >= n_edges) return;
    int quad = lane >> 4, l16 = lane & 15;
    int erow = e0 + l16; if (erow >= n_edges) erow = n_edges - 1;
    int ev = eid[erow];
    if (nt == 0 && quad == 0) src_csr[erow] = edge_src[ev];
    short8 a0 = {0,0,0,0,0,0,0,0};          // k = quad*8..+8 ; real only for k<16
    if (quad < 2) {
        const float4* ep = (const float4*)(edge_data + (size_t)ev*ED + quad*8);
        float4 x0 = ep[0], x1 = ep[1];
        a0[0]=(short)f2bf(x0.x); a0[1]=(short)f2bf(x0.y); a0[2]=(short)f2bf(x0.z); a0[3]=(short)f2bf(x0.w);
        a0[4]=(short)f2bf(x1.x); a0[5]=(short)f2bf(x1.y); a0[6]=(short)f2bf(x1.z); a0[7]=(short)f2bf(x1.w);
    }
    int n = nt*16 + l16;
    short8 b0 = *(const short8*)(W3T + (size_t)n*32 + quad*8);
    floatx4 z4 = {0.f,0.f,0.f,0.f};
    floatx4 d = __builtin_amdgcn_mfma_f32_16x16x32_bf16(a0, b0, z4, 0, 0, 0);
    #pragma unroll
    for (int r = 0; r < 4; ++r) {
        int e = e0 + quad*4 + r;
        if (e >= n_edges) break;
        Cb[(size_t)e*SD + n] = f2bf(d[r]);
    }
}

// Per-iter: [A|B] = hb @ [W1|W2] (+b_msg on A), bf16 out. Wave = 16 nodes x 16 cols.
__global__ __launch_bounds__(256) void ab_mfma_kernel(
        const unsigned short* __restrict__ hb, const unsigned short* __restrict__ WabT,
        const float* __restrict__ b_msg,
        unsigned short* __restrict__ Ab, unsigned short* __restrict__ Bb, int n_nodes) {
    int w = blockIdx.x * 4 + (threadIdx.x >> 6);
    int lane = threadIdx.x & 63;
    int mt = w >> 3, nt = w & 7;
    int m0 = mt * 16;
    if (m0 >= n_nodes) return;
    int quad = lane >> 4, l16 = lane & 15;
    int mrow = m0 + l16; if (mrow >= n_nodes) mrow = n_nodes - 1;
    const short8* ap = (const short8*)(hb + (size_t)mrow*SD + quad*8);
    short8 a0 = ap[0], a1 = ap[4];          // k and k+32
    int ncol = nt*16 + l16;
    const short8* bp = (const short8*)(WabT + (size_t)ncol*SD + quad*8);
    short8 b0 = bp[0], b1 = bp[4];
    floatx4 d = {0.f,0.f,0.f,0.f};
    d = __builtin_amdgcn_mfma_f32_16x16x32_bf16(a0, b0, d, 0, 0, 0);
    d = __builtin_amdgcn_mfma_f32_16x16x32_bf16(a1, b1, d, 0, 0, 0);
    int j = nt*16 + l16;
    float bias = (j < 64) ? b_msg[j] : 0.f;
    #pragma unroll
    for (int r = 0; r < 4; ++r) {
        int m = m0 + quad*4 + r;
        if (m >= n_nodes) break;
        float v = d[r] + bias;
        if (j < 64) Ab[(size_t)m*SD + j]        = f2bf(v);
        else        Bb[(size_t)m*SD + (j - 64)] = f2bf(v);
    }
}

// Aggregation: m_acc[n][j] (=|+=) sum_e relu(A[n][j] + B[src][j] + C[i][j]); writes mb bf16.
// Wave per node; 16-edge chunks -> 16 independent B/C gathers in flight.
template<int FIRST>
__global__ __launch_bounds__(256) void agg_kernel(
        const unsigned short* __restrict__ Ab, const unsigned short* __restrict__ Bb,
        const unsigned short* __restrict__ Cb, const int* __restrict__ src_csr,
        const int* __restrict__ row_ptr,
        float* __restrict__ m_acc, unsigned short* __restrict__ mb, int n_nodes) {
    int lane = threadIdx.x & 63;
    int wid = blockIdx.x * 4 + (threadIdx.x >> 6);
    wid = __builtin_amdgcn_readfirstlane(wid);
    int nw = gridDim.x * 4;
    for (int n = wid; n < n_nodes; n += nw) {
        int e0 = row_ptr[n], e1 = row_ptr[n + 1];
        float acc = 0.f;
        if (e0 < e1) {
            float a = bf2f(Ab[(size_t)n*SD + lane]);
            for (int i = e0; i < e1; i += 16) {
                int idx16 = i + (lane & 15); if (idx16 >= e1) idx16 = e1 - 1;
                int sv = src_csr[idx16];
                int srcs[16];
                #pragma unroll
                for (int t = 0; t < 16; ++t) srcs[t] = __builtin_amdgcn_readlane(sv, t);
                float bv[16], cv[16];
                #pragma unroll
                for (int t = 0; t < 16; ++t) {
                    int idx = i + t; if (idx >= e1) idx = e1 - 1;
                    bv[t] = bf2f(Bb[(size_t)srcs[t]*SD + lane]);
                    cv[t] = bf2f(Cb[(size_t)idx*SD + lane]);
                }
                int cnt = e1 - i;
                #pragma unroll
                for (int t = 0; t < 16; ++t)
                    if (t < cnt) acc += fmaxf(a + bv[t] + cv[t], 0.f);
            }
        }
        float base = FIRST ? 0.f : m_acc[(size_t)n*SD + lane];
        float nv = base + acc;
        m_acc[(size_t)n*SD + lane] = nv;
        mb[(size_t)n*SD + lane] = f2bf(nv);
    }
}

// GRU via MFMA: wave = 16 nodes x 16 gate-cols (jt). GI = mb@W_i, GH = hbr@W_h for
// r/z/n tiles; the (j, j+64, j+128) triple lands in the same lane/reg slot -> gates
// fully in-register. h updated fp32; bf16 written to ping-pong buffer hbw.
__global__ __launch_bounds__(256) void gru_mfma_kernel(
        float* __restrict__ h, const unsigned short* __restrict__ hbr,
        unsigned short* __restrict__ hbw, const unsigned short* __restrict__ mb,
        const unsigned short* __restrict__ WiT, const unsigned short* __restrict__ WhT,
        const float* __restrict__ b_i, const float* __restrict__ b_h, int n_nodes) {
    int w = blockIdx.x * 4 + (threadIdx.x >> 6);
    int lane = threadIdx.x & 63;
    int mt = w >> 2, jt = w & 3;
    int m0 = mt * 16;
    if (m0 >= n_nodes) return;
    int quad = lane >> 4, l16 = lane & 15;
    int mrow = m0 + l16; if (mrow >= n_nodes) mrow = n_nodes - 1;
    const short8* hp = (const short8*)(hbr + (size_t)mrow*SD + quad*8);
    short8 ha0 = hp[0], ha1 = hp[4];
    const short8* mp = (const short8*)(mb + (size_t)mrow*SD + quad*8);
    short8 ma0 = mp[0], ma1 = mp[4];
    int j0 = jt * 16;
    floatx4 di[3], dh[3];
    floatx4 z4 = {0.f,0.f,0.f,0.f};
    #pragma unroll
    for (int g = 0; g < 3; ++g) {
        int n = g*64 + j0 + l16;
        const short8* bi = (const short8*)(WiT + (size_t)n*SD + quad*8);
        const short8* bh = (const short8*)(WhT + (size_t)n*SD + quad*8);
        di[g] = __builtin_amdgcn_mfma_f32_16x16x32_bf16(ma0, bi[0], z4,    0, 0, 0);
        di[g] = __builtin_amdgcn_mfma_f32_16x16x32_bf16(ma1, bi[4], di[g], 0, 0, 0);
        dh[g] = __builtin_amdgcn_mfma_f32_16x16x32_bf16(ha0, bh[0], z4,    0, 0, 0);
        dh[g] = __builtin_amdgcn_mfma_f32_16x16x32_bf16(ha1, bh[4], dh[g], 0, 0, 0);
    }
    int j = j0 + l16;
    float bir = b_i[j], biz = b_i[64+j], bin = b_i[128+j];
    float bhr = b_h[j], bhz = b_h[64+j], bhn = b_h[128+j];
    #pragma unroll
    for (int r = 0; r < 4; ++r) {
        int m = m0 + quad*4 + r;
        if (m >= n_nodes) break;
        float rg = sigmoid_f(di[0][r] + bir + dh[0][r] + bhr);
        float zg = sigmoid_f(di[1][r] + biz + dh[1][r] + bhz);
        float ng = tanh_f(di[2][r] + bin + rg * (dh[2][r] + bhn));
        float hold = h[(size_t)m*SD + j];
        float hnew = (1.f - zg) * ng + zg * hold;
        h[(size_t)m*SD + j]  = hnew;
        hbw[(size_t)m*SD + j] = f2bf(hnew);
    }
}

// Readout: LDS-staged 128-node tile, thread-per-node MLP, shuffle-reduce, 32 atomics/block.
__global__ __launch_bounds__(128) void readout_kernel(
        const float* __restrict__ h, const float* __restrict__ W_r1, const float* __restrict__ b_r1,
        const float* __restrict__ W_r2, const float* __restrict__ b_r2,
        float* __restrict__ out, int n_nodes) {
    __shared__ float hs[128 * 65];
    __shared__ float osum[2 * RD];
    int tile0 = blockIdx.x * 128;
    #pragma unroll
    for (int j = 0; j < 16; ++j) {
        int f = threadIdx.x + j * 128;
        int row = f >> 4, c4 = (f & 15) * 4;
        int n = tile0 + row;
        float4 v = make_float4(0.f, 0.f, 0.f, 0.f);
        if (n < n_nodes) v = ((const float4*)(h + (size_t)n * SD))[f & 15];
        hs[row*65 + c4 + 0] = v.x;
        hs[row*65 + c4 + 1] = v.y;
        hs[row*65 + c4 + 2] = v.z;
        hs[row*65 + c4 + 3] = v.w;
    }
    __syncthreads();
    float o[RD];
    #pragma unroll
    for (int c = 0; c < RD; ++c) o[c] = 0.f;
    int n = tile0 + threadIdx.x;
    if (n < n_nodes) {
        const float* hr = hs + threadIdx.x * 65;
        float t[RH];
        #pragma unroll
        for (int i = 0; i < RH; ++i) t[i] = b_r1[i];
        #pragma unroll 4
        for (int k = 0; k < SD; ++k) {
            float hv = hr[k];
            #pragma unroll
            for (int i = 0; i < RH; ++i) t[i] += hv * W_r1[k*RH + i];
        }
        #pragma unroll
        for (int i = 0; i < RH; ++i) t[i] = fmaxf(t[i], 0.f);
        #pragma unroll
        for (int c = 0; c < RD; ++c) {
            float s = b_r2[c];
            #pragma unroll
            for (int i = 0; i < RH; ++i) s += t[i] * W_r2[i*RD + c];
            o[c] = s;
        }
    }
    int lane = threadIdx.x & 63;
    int wv = threadIdx.x >> 6;
    #pragma unroll
    for (int c = 0; c < RD; ++c) {
        float v = o[c];
        for (int off = 32; off > 0; off >>= 1) v += __shfl_down(v, off);
        if (lane == 0) osum[wv*RD + c] = v;
    }
    __syncthreads();
    if (threadIdx.x < RD) atomicAdd(&out[threadIdx.x], osum[threadIdx.x] + osum[RD + threadIdx.x]);
}

extern "C" void kernel_launch(void* const* d_in, const int* in_sizes, int n_in,
                              void* d_out, int out_size, void* d_ws, size_t ws_size,
                              hipStream_t stream) {
    const float* node_data = (const float*)d_in[0];
    const float* edge_data = (const float*)d_in[1];
    const int*   edge_src  = (const int*)d_in[2];
    const int*   edge_dst  = (const int*)d_in[3];
    const float* W_embed   = (const float*)d_in[4];
    const float* b_embed   = (const float*)d_in[5];
    const float* W_msg     = (const float*)d_in[6];
    const float* b_msg     = (const float*)d_in[7];
    const float* W_i       = (const float*)d_in[8];
    const float* b_i       = (const float*)d_in[9];
    const float* W_h       = (const float*)d_in[10];
    const float* b_h       = (const float*)d_in[11];
    const float* W_r1      = (const float*)d_in[12];
    const float* b_r1      = (const float*)d_in[13];
    const float* W_r2      = (const float*)d_in[14];
    const float* b_r2      = (const float*)d_in[15];

    int n_nodes = in_sizes[0] / VD;    // 20000
    int n_edges = in_sizes[2];         // 320000

    char* ws = (char*)d_ws;
    size_t off = 0;
    auto alloc = [&](size_t bytes) {
        void* p = ws + off;
        off = (off + bytes + 255) & ~(size_t)255;
        return p;
    };
    float* h            = (float*)alloc((size_t)n_nodes * SD * sizeof(float));
    float* m_acc        = (float*)alloc((size_t)n_nodes * SD * sizeof(float));
    unsigned short* hbA = (unsigned short*)alloc((size_t)n_nodes * SD * 2);
    unsigned short* hbB = (unsigned short*)alloc((size_t)n_nodes * SD * 2);
    unsigned short* mb  = (unsigned short*)alloc((size_t)n_nodes * SD * 2);
    unsigned short* Ab  = (unsigned short*)alloc((size_t)n_nodes * SD * 2);
    unsigned short* Bb  = (unsigned short*)alloc((size_t)n_nodes * SD * 2);
    unsigned short* Cb  = (unsigned short*)alloc((size_t)n_edges * SD * 2);
    int*   src_csr      = (int*)alloc((size_t)n_edges * sizeof(int));
    int*   deg          = (int*)alloc((size_t)n_nodes * sizeof(int));
    int*   row_ptr      = (int*)alloc((size_t)(n_nodes + 1) * sizeof(int));
    int*   fillc        = (int*)alloc((size_t)n_nodes * sizeof(int));
    int*   eid          = (int*)alloc((size_t)n_edges * sizeof(int));
    unsigned short* WabT = (unsigned short*)alloc(128*64*2);
    unsigned short* WiT  = (unsigned short*)alloc(192*64*2);
    unsigned short* WhT  = (unsigned short*)alloc(192*64*2);
    unsigned short* W3T  = (unsigned short*)alloc(64*32*2);
    (void)ws_size; (void)n_in;

    hipMemsetAsync(deg,   0, (size_t)n_nodes * sizeof(int), stream);
    hipMemsetAsync(fillc, 0, (size_t)n_nodes * sizeof(int), stream);
    hipMemsetAsync(d_out, 0, (size_t)out_size * sizeof(float), stream);

    embed_kernel<<<(n_nodes*SD + 255)/256, 256, 0, stream>>>(node_data, W_embed, b_embed,
                                                             h, hbA, n_nodes);
    prep_w_kernel<<<(128*64 + 192*64 + 64*32 + 255)/256, 256, 0, stream>>>(
        W_msg, W_i, W_h, WabT, WiT, WhT, W3T);

    hist_kernel<<<(n_edges + 255)/256, 256, 0, stream>>>(edge_dst, deg, n_edges);
    scan_kernel<<<1, 1024, 0, stream>>>(deg, row_ptr, n_nodes, n_edges);
    fill_kernel<<<(n_edges + 255)/256, 256, 0, stream>>>(edge_dst, row_ptr, fillc, eid, n_edges);

    int ec_waves = ((n_edges + 15)/16) * 4;
    edgeconst_kernel<<<(ec_waves + 3)/4, 256, 0, stream>>>(eid, edge_src, edge_data, W3T,
                                                           src_csr, Cb, n_edges);

    int mtiles = (n_nodes + 15) / 16;
    int ab_blocks  = (mtiles * 8 + 3) / 4;
    int agg_blocks = (n_nodes + 3) / 4;
    int gru_blocks = (mtiles * 4 + 3) / 4;
    for (int it = 0; it < N_ITERS; ++it) {
        unsigned short* hbr = (it & 1) ? hbB : hbA;
        unsigned short* hbw = (it & 1) ? hbA : hbB;
        ab_mfma_kernel<<<ab_blocks, 256, 0, stream>>>(hbr, WabT, b_msg, Ab, Bb, n_nodes);
        if (it == 0)
            agg_kernel<1><<<agg_blocks, 256, 0, stream>>>(Ab, Bb, Cb, src_csr, row_ptr,
                                                          m_acc, mb, n_nodes);
        else
            agg_kernel<0><<<agg_blocks, 256, 0, stream>>>(Ab, Bb, Cb, src_csr, row_ptr,
                                                          m_acc, mb, n_nodes);
        gru_mfma_kernel<<<gru_blocks, 256, 0, stream>>>(h, hbr, hbw, mb, WiT, WhT,
                                                        b_i, b_h, n_nodes);
    }

    readout_kernel<<<(n_nodes + 127)/128, 128, 0, stream>>>(h, W_r1, b_r1, W_r2, b_r2,
                                                            (float*)d_out, n_nodes);
}

// Round 6
// 333.114 us; speedup vs baseline: 2.8017x; 1.0584x over previous
//
#include <hip/hip_runtime.h>

static constexpr int VD = 16;     // vertex feature dim
static constexpr int SD = 64;     // state dim
static constexpr int ED = 16;     // edge feature dim
static constexpr int RH = 10, RD = 32;
static constexpr int N_ITERS = 3;

typedef __attribute__((ext_vector_type(8))) short short8;
typedef __attribute__((ext_vector_type(4))) float floatx4;

__device__ __forceinline__ float sigmoid_f(float x) {
    return 1.f / (1.f + __expf(-x));
}
__device__ __forceinline__ float tanh_f(float x) {
    x = fminf(fmaxf(x, -20.f), 20.f);
    float e = __expf(2.f * x);
    return (e - 1.f) / (e + 1.f);
}
__device__ __forceinline__ unsigned short f2bf(float x) {   // round-to-nearest-even
    unsigned u = __float_as_uint(x);
    unsigned r = (u + 0x7FFFu + ((u >> 16) & 1u)) >> 16;
    return (unsigned short)r;
}
__device__ __forceinline__ float bf2f(unsigned short s) {
    return __uint_as_float(((unsigned)s) << 16);
}

// h[n][j] = node_data[n] @ W_embed[:,j] + b_embed[j]; also writes bf16 copy.
__global__ void embed_kernel(const float* __restrict__ node_data,
                             const float* __restrict__ W_embed,
                             const float* __restrict__ b_embed,
                             float* __restrict__ h, unsigned short* __restrict__ hb,
                             int n_nodes) {
    int gid = blockIdx.x * blockDim.x + threadIdx.x;
    int n = gid >> 6, j = gid & 63;
    if (n >= n_nodes) return;
    const float* nd = node_data + (size_t)n * VD;
    float acc = b_embed[j];
    #pragma unroll
    for (int k = 0; k < VD; ++k) acc += nd[k] * W_embed[k*SD + j];
    h[(size_t)n*SD + j] = acc;
    hb[(size_t)n*SD + j] = f2bf(acc);
}

// One-time bf16 weight transposes for MFMA B-operands ([n][k] layout).
__global__ void prep_w_kernel(const float* __restrict__ W_msg,
                              const float* __restrict__ W_i, const float* __restrict__ W_h,
                              unsigned short* __restrict__ WabT, unsigned short* __restrict__ WiT,
                              unsigned short* __restrict__ WhT, unsigned short* __restrict__ W3T) {
    int i = blockIdx.x * blockDim.x + threadIdx.x;
    if (i < 128*64) {                       // WabT[n][k]: n<64 -> W1 col n; else W2 col n-64
        int n = i >> 6, k = i & 63;
        WabT[i] = f2bf(W_msg[((n < 64 ? 0 : 64) + k)*64 + (n & 63)]);
    }
    int j = i - 128*64;
    if (j >= 0 && j < 192*64) {             // WiT/WhT[n][k] = W[k][n]
        int n = j >> 6, k = j & 63;
        WiT[j] = f2bf(W_i[k*192 + n]);
        WhT[j] = f2bf(W_h[k*192 + n]);
    }
    int l = i - 128*64 - 192*64;
    if (l >= 0 && l < 64*32) {              // W3T[n][k], k padded 16->32 with zeros
        int n = l >> 5, k = l & 31;
        W3T[l] = (k < 16) ? f2bf(W_msg[(128+k)*64 + n]) : (unsigned short)0;
    }
}

__global__ void hist_kernel(const int* __restrict__ edge_dst, int* __restrict__ deg, int n_edges) {
    for (int e = blockIdx.x*blockDim.x + threadIdx.x; e < n_edges; e += gridDim.x*blockDim.x)
        atomicAdd(&deg[edge_dst[e]], 1);
}

// Exclusive scan of EVEN-PADDED degrees -> row_ptr (every node's range starts even,
// so the pair-interleaved C layout stays aligned per node).
__global__ __launch_bounds__(1024) void scan_kernel(const int* __restrict__ deg,
                                                    int* __restrict__ row_ptr,
                                                    int n_nodes) {
    __shared__ int s[1024];
    int lid = threadIdx.x;
    int C = (n_nodes + 1023) >> 10;
    int start = lid * C;
    int lsum = 0;
    for (int i = 0; i < C; ++i) {
        int idx = start + i;
        if (idx < n_nodes) lsum += (deg[idx] + 1) & ~1;
    }
    s[lid] = lsum; __syncthreads();
    for (int off = 1; off < 1024; off <<= 1) {
        int v = s[lid];
        int add = (lid >= off) ? s[lid - off] : 0;
        __syncthreads();
        s[lid] = v + add;
        __syncthreads();
    }
    int run = s[lid] - lsum;
    for (int i = 0; i < C; ++i) {
        int idx = start + i;
        if (idx < n_nodes) { row_ptr[idx] = run; run += (deg[idx] + 1) & ~1; }
    }
    if (lid == 1023) row_ptr[n_nodes] = run;   // padded total (not used downstream)
}

__global__ void fill_kernel(const int* __restrict__ edge_dst, const int* __restrict__ row_ptr,
                            int* __restrict__ fillc, int* __restrict__ eid, int n_edges) {
    for (int e = blockIdx.x*blockDim.x + threadIdx.x; e < n_edges; e += gridDim.x*blockDim.x) {
        int d = edge_dst[e];
        int ofs = atomicAdd(&fillc[d], 1);
        eid[row_ptr[d] + ofs] = e;
    }
}

// Once: Cp[pair][col][2] = edge_data[eid[pos]] @ W3 (bf16, pair-interleaved), src_csr gather.
// ONE wave per 16-position tile: A-frag loaded once, 4 MFMAs over col tiles.
// Pad positions have eid==0 (memset) -> safe loads; agg masks them by deg.
__global__ __launch_bounds__(256) void edgeconst_kernel(
        const int* __restrict__ eid, const int* __restrict__ edge_src,
        const float* __restrict__ edge_data, const unsigned short* __restrict__ W3T,
        int* __restrict__ src_csr, unsigned short* __restrict__ Cp, int Lmax) {
    int w = blockIdx.x * 4 + (threadIdx.x >> 6);
    int lane = threadIdx.x & 63;
    int e0 = w * 16;
    if (e0 >= Lmax) return;
    int quad = lane >> 4, l16 = lane & 15;
    int erow = e0 + l16;
    int ev = eid[erow];                      // coalesced; 0 for pads
    if (quad == 0) src_csr[erow] = edge_src[ev];
    short8 a0 = {0,0,0,0,0,0,0,0};           // k = quad*8..+8; real only k<16
    if (quad < 2) {
        const float4* ep = (const float4*)(edge_data + (size_t)ev*ED + quad*8);
        float4 x0 = ep[0], x1 = ep[1];
        a0[0]=(short)f2bf(x0.x); a0[1]=(short)f2bf(x0.y); a0[2]=(short)f2bf(x0.z); a0[3]=(short)f2bf(x0.w);
        a0[4]=(short)f2bf(x1.x); a0[5]=(short)f2bf(x1.y); a0[6]=(short)f2bf(x1.z); a0[7]=(short)f2bf(x1.w);
    }
    floatx4 z4 = {0.f,0.f,0.f,0.f};
    #pragma unroll
    for (int nt = 0; nt < 4; ++nt) {
        int n = nt*16 + l16;
        short8 b0 = *(const short8*)(W3T + (size_t)n*32 + quad*8);
        floatx4 d = __builtin_amdgcn_mfma_f32_16x16x32_bf16(a0, b0, z4, 0, 0, 0);
        #pragma unroll
        for (int r = 0; r < 4; ++r) {
            int e = e0 + quad*4 + r;         // e0 is 16-aligned -> pair index e>>1, slot e&1
            Cp[(size_t)(e >> 1)*128 + n*2 + (e & 1)] = f2bf(d[r]);
        }
    }
}

// Iter-0 only: [A|B] = hb @ [W1|W2] (+b_msg on A), bf16 out. Wave = 16 nodes x 16 cols.
__global__ __launch_bounds__(256) void ab_mfma_kernel(
        const unsigned short* __restrict__ hb, const unsigned short* __restrict__ WabT,
        const float* __restrict__ b_msg,
        unsigned short* __restrict__ Ab, unsigned short* __restrict__ Bb, int n_nodes) {
    int w = blockIdx.x * 4 + (threadIdx.x >> 6);
    int lane = threadIdx.x & 63;
    int mt = w >> 3, nt = w & 7;
    int m0 = mt * 16;
    if (m0 >= n_nodes) return;
    int quad = lane >> 4, l16 = lane & 15;
    int mrow = m0 + l16; if (mrow >= n_nodes) mrow = n_nodes - 1;
    const short8* ap = (const short8*)(hb + (size_t)mrow*SD + quad*8);
    short8 a0 = ap[0], a1 = ap[4];
    int ncol = nt*16 + l16;
    const short8* bp = (const short8*)(WabT + (size_t)ncol*SD + quad*8);
    short8 b0 = bp[0], b1 = bp[4];
    floatx4 d = {0.f,0.f,0.f,0.f};
    d = __builtin_amdgcn_mfma_f32_16x16x32_bf16(a0, b0, d, 0, 0, 0);
    d = __builtin_amdgcn_mfma_f32_16x16x32_bf16(a1, b1, d, 0, 0, 0);
    int j = nt*16 + l16;
    float bias = (j < 64) ? b_msg[j] : 0.f;
    #pragma unroll
    for (int r = 0; r < 4; ++r) {
        int m = m0 + quad*4 + r;
        if (m >= n_nodes) break;
        float v = d[r] + bias;
        if (j < 64) Ab[(size_t)m*SD + j]        = f2bf(v);
        else        Bb[(size_t)m*SD + (j - 64)] = f2bf(v);
    }
}

// Aggregation: m_acc[n][j] (=|+=) sum_e relu(A[n][j] + B[src][j] + C[e][j]); writes mb bf16.
// Wave per node; row_ptr offsets even -> Cp ushort2 loads cover 2 edges each.
template<int FIRST>
__global__ __launch_bounds__(256) void agg_kernel(
        const unsigned short* __restrict__ Ab, const unsigned short* __restrict__ Bb,
        const unsigned short* __restrict__ Cp, const int* __restrict__ src_csr,
        const int* __restrict__ row_ptr, const int* __restrict__ deg,
        float* __restrict__ m_acc, unsigned short* __restrict__ mb, int n_nodes) {
    int lane = threadIdx.x & 63;
    int wid = blockIdx.x * 4 + (threadIdx.x >> 6);
    wid = __builtin_amdgcn_readfirstlane(wid);
    int nw = gridDim.x * 4;
    for (int n = wid; n < n_nodes; n += nw) {
        int e0 = row_ptr[n];                 // even
        int cnt_total = deg[n];
        int e1 = e0 + cnt_total;
        float acc = 0.f;
        if (cnt_total > 0) {
            float a = bf2f(Ab[(size_t)n*SD + lane]);
            for (int i = e0; i < e1; i += 16) {
                int idx16 = i + (lane & 15); if (idx16 >= e1) idx16 = e1 - 1;
                int sv = src_csr[idx16];
                int srcs[16];
                #pragma unroll
                for (int t = 0; t < 16; ++t) srcs[t] = __builtin_amdgcn_readlane(sv, t);
                float bv[16];
                #pragma unroll
                for (int t = 0; t < 16; ++t) bv[t] = bf2f(Bb[(size_t)srcs[t]*SD + lane]);
                unsigned cp2[8];
                #pragma unroll
                for (int t2 = 0; t2 < 8; ++t2)      // 2 edges per 4B load (pair layout)
                    cp2[t2] = *(const unsigned*)(Cp + (size_t)((i >> 1) + t2)*128 + lane*2);
                int cnt = e1 - i;
                #pragma unroll
                for (int t = 0; t < 16; ++t) {
                    if (t < cnt) {
                        float cv = bf2f((unsigned short)((t & 1) ? (cp2[t>>1] >> 16)
                                                                 : (cp2[t>>1] & 0xFFFF)));
                        acc += fmaxf(a + bv[t] + cv, 0.f);
                    }
                }
            }
        }
        float base = FIRST ? 0.f : m_acc[(size_t)n*SD + lane];
        float nv = base + acc;
        m_acc[(size_t)n*SD + lane] = nv;
        mb[(size_t)n*SD + lane] = f2bf(nv);
    }
}

// GRU + fused next-iter [A|B]: block = 16-node tile, 4 waves (jt = 16-col slices).
// Phase 1: GI = mb@W_i, GH = hbr@W_h (12 MFMAs), gates, hnew -> h/hbw + LDS tile.
// Phase 2 (DO_AB): [A|B] tiles from LDS hnew (4 MFMAs total per wave pair-of-tiles).
template<int DO_AB>
__global__ __launch_bounds__(256) void gru_fused_kernel(
        float* __restrict__ h, const unsigned short* __restrict__ hbr,
        unsigned short* __restrict__ hbw, const unsigned short* __restrict__ mb,
        const unsigned short* __restrict__ WiT, const unsigned short* __restrict__ WhT,
        const float* __restrict__ b_i, const float* __restrict__ b_h,
        const unsigned short* __restrict__ WabT, const float* __restrict__ b_msg,
        unsigned short* __restrict__ Ab, unsigned short* __restrict__ Bb, int n_nodes) {
    __shared__ unsigned short hs[16 * 68];   // stride 68: staggers bank phases
    int jt = threadIdx.x >> 6;
    int lane = threadIdx.x & 63;
    int m0 = blockIdx.x * 16;
    if (m0 >= n_nodes) return;
    int quad = lane >> 4, l16 = lane & 15;
    int mrow = m0 + l16; if (mrow >= n_nodes) mrow = n_nodes - 1;
    const short8* hp = (const short8*)(hbr + (size_t)mrow*SD + quad*8);
    short8 ha0 = hp[0], ha1 = hp[4];
    const short8* mp = (const short8*)(mb + (size_t)mrow*SD + quad*8);
    short8 ma0 = mp[0], ma1 = mp[4];
    int j0 = jt * 16;
    floatx4 di[3], dh[3];
    floatx4 z4 = {0.f,0.f,0.f,0.f};
    #pragma unroll
    for (int g = 0; g < 3; ++g) {
        int n = g*64 + j0 + l16;
        const short8* bi = (const short8*)(WiT + (size_t)n*SD + quad*8);
        const short8* bh = (const short8*)(WhT + (size_t)n*SD + quad*8);
        di[g] = __builtin_amdgcn_mfma_f32_16x16x32_bf16(ma0, bi[0], z4,    0, 0, 0);
        di[g] = __builtin_amdgcn_mfma_f32_16x16x32_bf16(ma1, bi[4], di[g], 0, 0, 0);
        dh[g] = __builtin_amdgcn_mfma_f32_16x16x32_bf16(ha0, bh[0], z4,    0, 0, 0);
        dh[g] = __builtin_amdgcn_mfma_f32_16x16x32_bf16(ha1, bh[4], dh[g], 0, 0, 0);
    }
    int j = j0 + l16;
    float bir = b_i[j], biz = b_i[64+j], bin = b_i[128+j];
    float bhr = b_h[j], bhz = b_h[64+j], bhn = b_h[128+j];
    #pragma unroll
    for (int r = 0; r < 4; ++r) {
        int m = m0 + quad*4 + r;
        if (m >= n_nodes) break;
        float rg = sigmoid_f(di[0][r] + bir + dh[0][r] + bhr);
        float zg = sigmoid_f(di[1][r] + biz + dh[1][r] + bhz);
        float ng = tanh_f(di[2][r] + bin + rg * (dh[2][r] + bhn));
        float hold = h[(size_t)m*SD + j];
        float hnew = (1.f - zg) * ng + zg * hold;
        unsigned short hb16 = f2bf(hnew);
        h[(size_t)m*SD + j]   = hnew;
        hbw[(size_t)m*SD + j] = hb16;
        hs[(quad*4 + r)*68 + j] = hb16;
    }
    if (DO_AB) {
        __syncthreads();
        // A-frag of hnew tile from LDS (rows = l16, k = quad*8.. and +32)
        short8 a0 = *(const short8*)(hs + l16*68 + quad*8);
        short8 a1 = *(const short8*)(hs + l16*68 + 32 + quad*8);
        #pragma unroll
        for (int s = 0; s < 2; ++s) {
            int tt = jt + 4*s;               // s=0 -> A tiles, s=1 -> B tiles
            int ncol = tt*16 + l16;
            const short8* bp = (const short8*)(WabT + (size_t)ncol*SD + quad*8);
            floatx4 d = __builtin_amdgcn_mfma_f32_16x16x32_bf16(a0, bp[0], z4, 0, 0, 0);
            d = __builtin_amdgcn_mfma_f32_16x16x32_bf16(a1, bp[4], d, 0, 0, 0);
            float bias = (s == 0) ? b_msg[ncol] : 0.f;
            int jc = jt*16 + l16;            // output col within A or B
            #pragma unroll
            for (int r = 0; r < 4; ++r) {
                int m = m0 + quad*4 + r;
                if (m >= n_nodes) break;
                float v = d[r] + bias;
                if (s == 0) Ab[(size_t)m*SD + jc] = f2bf(v);
                else        Bb[(size_t)m*SD + jc] = f2bf(v);
            }
        }
    }
}

// Readout: LDS-staged 128-node tile, thread-per-node MLP, shuffle-reduce, 32 atomics/block.
__global__ __launch_bounds__(128) void readout_kernel(
        const float* __restrict__ h, const float* __restrict__ W_r1, const float* __restrict__ b_r1,
        const float* __restrict__ W_r2, const float* __restrict__ b_r2,
        float* __restrict__ out, int n_nodes) {
    __shared__ float hsr[128 * 65];
    __shared__ float osum[2 * RD];
    int tile0 = blockIdx.x * 128;
    #pragma unroll
    for (int j = 0; j < 16; ++j) {
        int f = threadIdx.x + j * 128;
        int row = f >> 4, c4 = (f & 15) * 4;
        int n = tile0 + row;
        float4 v = make_float4(0.f, 0.f, 0.f, 0.f);
        if (n < n_nodes) v = ((const float4*)(h + (size_t)n * SD))[f & 15];
        hsr[row*65 + c4 + 0] = v.x;
        hsr[row*65 + c4 + 1] = v.y;
        hsr[row*65 + c4 + 2] = v.z;
        hsr[row*65 + c4 + 3] = v.w;
    }
    __syncthreads();
    float o[RD];
    #pragma unroll
    for (int c = 0; c < RD; ++c) o[c] = 0.f;
    int n = tile0 + threadIdx.x;
    if (n < n_nodes) {
        const float* hr = hsr + threadIdx.x * 65;
        float t[RH];
        #pragma unroll
        for (int i = 0; i < RH; ++i) t[i] = b_r1[i];
        #pragma unroll 4
        for (int k = 0; k < SD; ++k) {
            float hv = hr[k];
            #pragma unroll
            for (int i = 0; i < RH; ++i) t[i] += hv * W_r1[k*RH + i];
        }
        #pragma unroll
        for (int i = 0; i < RH; ++i) t[i] = fmaxf(t[i], 0.f);
        #pragma unroll
        for (int c = 0; c < RD; ++c) {
            float s = b_r2[c];
            #pragma unroll
            for (int i = 0; i < RH; ++i) s += t[i] * W_r2[i*RD + c];
            o[c] = s;
        }
    }
    int lane = threadIdx.x & 63;
    int wv = threadIdx.x >> 6;
    #pragma unroll
    for (int c = 0; c < RD; ++c) {
        float v = o[c];
        for (int off = 32; off > 0; off >>= 1) v += __shfl_down(v, off);
        if (lane == 0) osum[wv*RD + c] = v;
    }
    __syncthreads();
    if (threadIdx.x < RD) atomicAdd(&out[threadIdx.x], osum[threadIdx.x] + osum[RD + threadIdx.x]);
}

extern "C" void kernel_launch(void* const* d_in, const int* in_sizes, int n_in,
                              void* d_out, int out_size, void* d_ws, size_t ws_size,
                              hipStream_t stream) {
    const float* node_data = (const float*)d_in[0];
    const float* edge_data = (const float*)d_in[1];
    const int*   edge_src  = (const int*)d_in[2];
    const int*   edge_dst  = (const int*)d_in[3];
    const float* W_embed   = (const float*)d_in[4];
    const float* b_embed   = (const float*)d_in[5];
    const float* W_msg     = (const float*)d_in[6];
    const float* b_msg     = (const float*)d_in[7];
    const float* W_i       = (const float*)d_in[8];
    const float* b_i       = (const float*)d_in[9];
    const float* W_h       = (const float*)d_in[10];
    const float* b_h       = (const float*)d_in[11];
    const float* W_r1      = (const float*)d_in[12];
    const float* b_r1      = (const float*)d_in[13];
    const float* W_r2      = (const float*)d_in[14];
    const float* b_r2      = (const float*)d_in[15];

    int n_nodes = in_sizes[0] / VD;    // 20000
    int n_edges = in_sizes[2];         // 320000
    int Lmax = n_edges + n_nodes + 64; // padded CSR capacity (every node +1 worst case)

    char* ws = (char*)d_ws;
    size_t off = 0;
    auto alloc = [&](size_t bytes) {
        void* p = ws + off;
        off = (off + bytes + 255) & ~(size_t)255;
        return p;
    };
    float* h            = (float*)alloc((size_t)n_nodes * SD * sizeof(float));
    float* m_acc        = (float*)alloc((size_t)n_nodes * SD * sizeof(float));
    unsigned short* hbA = (unsigned short*)alloc((size_t)n_nodes * SD * 2);
    unsigned short* hbB = (unsigned short*)alloc((size_t)n_nodes * SD * 2);
    unsigned short* mb  = (unsigned short*)alloc((size_t)n_nodes * SD * 2);
    unsigned short* Ab  = (unsigned short*)alloc((size_t)n_nodes * SD * 2);
    unsigned short* Bb  = (unsigned short*)alloc((size_t)n_nodes * SD * 2);
    unsigned short* Cp  = (unsigned short*)alloc((size_t)(Lmax + 32) * SD * 2);
    int*   src_csr      = (int*)alloc((size_t)(Lmax + 32) * sizeof(int));
    int*   row_ptr      = (int*)alloc((size_t)(n_nodes + 1) * sizeof(int));
    // contiguous zero-init region: deg, fillc, eid (one memset)
    char*  zbase        = (char*)alloc(0);
    int*   deg          = (int*)alloc((size_t)n_nodes * sizeof(int));
    int*   fillc        = (int*)alloc((size_t)n_nodes * sizeof(int));
    int*   eid          = (int*)alloc((size_t)(Lmax + 32) * sizeof(int));
    char*  zend         = (char*)alloc(0);
    unsigned short* WabT = (unsigned short*)alloc(128*64*2);
    unsigned short* WiT  = (unsigned short*)alloc(192*64*2);
    unsigned short* WhT  = (unsigned short*)alloc(192*64*2);
    unsigned short* W3T  = (unsigned short*)alloc(64*32*2);
    (void)ws_size; (void)n_in;

    hipMemsetAsync(zbase, 0, (size_t)(zend - zbase), stream);
    hipMemsetAsync(d_out, 0, (size_t)out_size * sizeof(float), stream);

    embed_kernel<<<(n_nodes*SD + 255)/256, 256, 0, stream>>>(node_data, W_embed, b_embed,
                                                             h, hbA, n_nodes);
    prep_w_kernel<<<(128*64 + 192*64 + 64*32 + 255)/256, 256, 0, stream>>>(
        W_msg, W_i, W_h, WabT, WiT, WhT, W3T);

    hist_kernel<<<(n_edges + 255)/256, 256, 0, stream>>>(edge_dst, deg, n_edges);
    scan_kernel<<<1, 1024, 0, stream>>>(deg, row_ptr, n_nodes);
    fill_kernel<<<(n_edges + 255)/256, 256, 0, stream>>>(edge_dst, row_ptr, fillc, eid, n_edges);

    int ec_waves = (Lmax + 15) / 16;
    edgeconst_kernel<<<(ec_waves + 3)/4, 256, 0, stream>>>(eid, edge_src, edge_data, W3T,
                                                           src_csr, Cp, Lmax);

    int mtiles = (n_nodes + 15) / 16;
    int ab_blocks  = (mtiles * 8 + 3) / 4;
    int agg_blocks = (n_nodes + 3) / 4;
    ab_mfma_kernel<<<ab_blocks, 256, 0, stream>>>(hbA, WabT, b_msg, Ab, Bb, n_nodes);
    for (int it = 0; it < N_ITERS; ++it) {
        unsigned short* hbr = (it & 1) ? hbB : hbA;
        unsigned short* hbw = (it & 1) ? hbA : hbB;
        if (it == 0)
            agg_kernel<1><<<agg_blocks, 256, 0, stream>>>(Ab, Bb, Cp, src_csr, row_ptr, deg,
                                                          m_acc, mb, n_nodes);
        else
            agg_kernel<0><<<agg_blocks, 256, 0, stream>>>(Ab, Bb, Cp, src_csr, row_ptr, deg,
                                                          m_acc, mb, n_nodes);
        if (it < N_ITERS - 1)
            gru_fused_kernel<1><<<mtiles, 256, 0, stream>>>(h, hbr, hbw, mb, WiT, WhT,
                                                            b_i, b_h, WabT, b_msg, Ab, Bb, n_nodes);
        else
            gru_fused_kernel<0><<<mtiles, 256, 0, stream>>>(h, hbr, hbw, mb, WiT, WhT,
                                                            b_i, b_h, WabT, b_msg, Ab, Bb, n_nodes);
    }

    readout_kernel<<<(n_nodes + 127)/128, 128, 0, stream>>>(h, W_r1, b_r1, W_r2, b_r2,
                                                            (float*)d_out, n_nodes);
}

// Round 7
// 308.789 us; speedup vs baseline: 3.0224x; 1.0788x over previous
//
#include <hip/hip_runtime.h>

static constexpr int VD = 16;     // vertex feature dim
static constexpr int SD = 64;     // state dim
static constexpr int ED = 16;     // edge feature dim
static constexpr int RH = 10, RD = 32;
static constexpr int N_ITERS = 3;

typedef __attribute__((ext_vector_type(8))) short short8;
typedef __attribute__((ext_vector_type(4))) float floatx4;

__device__ __forceinline__ float sigmoid_f(float x) {
    return 1.f / (1.f + __expf(-x));
}
__device__ __forceinline__ float tanh_f(float x) {
    x = fminf(fmaxf(x, -20.f), 20.f);
    float e = __expf(2.f * x);
    return (e - 1.f) / (e + 1.f);
}
__device__ __forceinline__ unsigned short f2bf(float x) {   // round-to-nearest-even
    unsigned u = __float_as_uint(x);
    unsigned r = (u + 0x7FFFu + ((u >> 16) & 1u)) >> 16;
    return (unsigned short)r;
}
__device__ __forceinline__ float bf2f(unsigned short s) {
    return __uint_as_float(((unsigned)s) << 16);
}

// One-time bf16 weight transposes for MFMA B-operands ([n][k] layout).
__global__ void prep_w_kernel(const float* __restrict__ W_msg,
                              const float* __restrict__ W_i, const float* __restrict__ W_h,
                              const float* __restrict__ W_embed,
                              unsigned short* __restrict__ WabT, unsigned short* __restrict__ WiT,
                              unsigned short* __restrict__ WhT, unsigned short* __restrict__ W3T,
                              unsigned short* __restrict__ WeT) {
    int i = blockIdx.x * blockDim.x + threadIdx.x;
    if (i < 128*64) {                       // WabT[n][k]: n<64 -> W1 col n; else W2 col n-64
        int n = i >> 6, k = i & 63;
        WabT[i] = f2bf(W_msg[((n < 64 ? 0 : 64) + k)*64 + (n & 63)]);
    }
    int j = i - 128*64;
    if (j >= 0 && j < 192*64) {             // WiT/WhT[n][k] = W[k][n]
        int n = j >> 6, k = j & 63;
        WiT[j] = f2bf(W_i[k*192 + n]);
        WhT[j] = f2bf(W_h[k*192 + n]);
    }
    int l = i - 128*64 - 192*64;
    if (l >= 0 && l < 64*32) {              // W3T[n][k], k padded 16->32 with zeros
        int n = l >> 5, k = l & 31;
        W3T[l] = (k < 16) ? f2bf(W_msg[(128+k)*64 + n]) : (unsigned short)0;
    }
    int m = i - 128*64 - 192*64 - 64*32;
    if (m >= 0 && m < 64*32) {              // WeT[n][k], k padded 16->32 (embed)
        int n = m >> 5, k = m & 31;
        WeT[m] = (k < 16) ? f2bf(W_embed[k*64 + n]) : (unsigned short)0;
    }
}

__global__ void hist_kernel(const int* __restrict__ edge_dst, int* __restrict__ deg, int n_edges) {
    for (int e = blockIdx.x*blockDim.x + threadIdx.x; e < n_edges; e += gridDim.x*blockDim.x)
        atomicAdd(&deg[edge_dst[e]], 1);
}

// Exclusive scan of EVEN-PADDED degrees -> row_ptr (pair-aligned node ranges).
__global__ __launch_bounds__(1024) void scan_kernel(const int* __restrict__ deg,
                                                    int* __restrict__ row_ptr,
                                                    int n_nodes) {
    __shared__ int s[1024];
    int lid = threadIdx.x;
    int C = (n_nodes + 1023) >> 10;
    int start = lid * C;
    int lsum = 0;
    for (int i = 0; i < C; ++i) {
        int idx = start + i;
        if (idx < n_nodes) lsum += (deg[idx] + 1) & ~1;
    }
    s[lid] = lsum; __syncthreads();
    for (int off = 1; off < 1024; off <<= 1) {
        int v = s[lid];
        int add = (lid >= off) ? s[lid - off] : 0;
        __syncthreads();
        s[lid] = v + add;
        __syncthreads();
    }
    int run = s[lid] - lsum;
    for (int i = 0; i < C; ++i) {
        int idx = start + i;
        if (idx < n_nodes) { row_ptr[idx] = run; run += (deg[idx] + 1) & ~1; }
    }
    if (lid == 1023) row_ptr[n_nodes] = run;
}

__global__ void fill_kernel(const int* __restrict__ edge_dst, const int* __restrict__ row_ptr,
                            int* __restrict__ fillc, int* __restrict__ eid, int n_edges) {
    for (int e = blockIdx.x*blockDim.x + threadIdx.x; e < n_edges; e += gridDim.x*blockDim.x) {
        int d = edge_dst[e];
        int ofs = atomicAdd(&fillc[d], 1);
        eid[row_ptr[d] + ofs] = e;
    }
}

// Once: Cp[pair][col][2] = edge_data[eid[pos]] @ W3 (bf16 pair-interleaved) + src_csr gather.
// One wave per 16-position tile: A-frag loaded once, 4 MFMAs over col tiles.
__global__ __launch_bounds__(256) void edgeconst_kernel(
        const int* __restrict__ eid, const int* __restrict__ edge_src,
        const float* __restrict__ edge_data, const unsigned short* __restrict__ W3T,
        int* __restrict__ src_csr, unsigned short* __restrict__ Cp, int Lmax) {
    int w = blockIdx.x * 4 + (threadIdx.x >> 6);
    int lane = threadIdx.x & 63;
    int e0 = w * 16;
    if (e0 >= Lmax) return;
    int quad = lane >> 4, l16 = lane & 15;
    int erow = e0 + l16;
    int ev = eid[erow];                      // coalesced; 0 for pads
    if (quad == 0) src_csr[erow] = edge_src[ev];
    short8 a0 = {0,0,0,0,0,0,0,0};           // k = quad*8..+8; real only k<16
    if (quad < 2) {
        const float4* ep = (const float4*)(edge_data + (size_t)ev*ED + quad*8);
        float4 x0 = ep[0], x1 = ep[1];
        a0[0]=(short)f2bf(x0.x); a0[1]=(short)f2bf(x0.y); a0[2]=(short)f2bf(x0.z); a0[3]=(short)f2bf(x0.w);
        a0[4]=(short)f2bf(x1.x); a0[5]=(short)f2bf(x1.y); a0[6]=(short)f2bf(x1.z); a0[7]=(short)f2bf(x1.w);
    }
    floatx4 z4 = {0.f,0.f,0.f,0.f};
    #pragma unroll
    for (int nt = 0; nt < 4; ++nt) {
        int n = nt*16 + l16;
        short8 b0 = *(const short8*)(W3T + (size_t)n*32 + quad*8);
        floatx4 d = __builtin_amdgcn_mfma_f32_16x16x32_bf16(a0, b0, z4, 0, 0, 0);
        #pragma unroll
        for (int r = 0; r < 4; ++r) {
            int e = e0 + quad*4 + r;
            Cp[(size_t)(e >> 1)*128 + n*2 + (e & 1)] = f2bf(d[r]);
        }
    }
}

// Embed via MFMA (K=16 padded to 32) + fused iter-0 [A|B]. Block = 16-node tile, 4 waves.
__global__ __launch_bounds__(256) void embed_fused_kernel(
        const float* __restrict__ node_data, const unsigned short* __restrict__ WeT,
        const float* __restrict__ b_embed,
        float* __restrict__ h, unsigned short* __restrict__ hb,
        const unsigned short* __restrict__ WabT, const float* __restrict__ b_msg,
        unsigned short* __restrict__ Ab, unsigned short* __restrict__ Bb, int n_nodes) {
    __shared__ unsigned short hs[16 * 68];
    int jt = threadIdx.x >> 6, lane = threadIdx.x & 63;
    int m0 = blockIdx.x * 16;
    if (m0 >= n_nodes) return;
    int quad = lane >> 4, l16 = lane & 15;
    int mrow = m0 + l16; if (mrow >= n_nodes) mrow = n_nodes - 1;
    short8 a0 = {0,0,0,0,0,0,0,0};
    if (quad < 2) {
        const float4* np = (const float4*)(node_data + (size_t)mrow*VD + quad*8);
        float4 x0 = np[0], x1 = np[1];
        a0[0]=(short)f2bf(x0.x); a0[1]=(short)f2bf(x0.y); a0[2]=(short)f2bf(x0.z); a0[3]=(short)f2bf(x0.w);
        a0[4]=(short)f2bf(x1.x); a0[5]=(short)f2bf(x1.y); a0[6]=(short)f2bf(x1.z); a0[7]=(short)f2bf(x1.w);
    }
    int j = jt*16 + l16;
    short8 b0 = *(const short8*)(WeT + (size_t)j*32 + quad*8);
    floatx4 z4 = {0.f,0.f,0.f,0.f};
    floatx4 d = __builtin_amdgcn_mfma_f32_16x16x32_bf16(a0, b0, z4, 0, 0, 0);
    float bias = b_embed[j];
    #pragma unroll
    for (int r = 0; r < 4; ++r) {
        int m = m0 + quad*4 + r;
        float v = d[r] + bias;
        unsigned short v16 = f2bf(v);
        hs[(quad*4 + r)*68 + j] = v16;
        if (m < n_nodes) {
            h[(size_t)m*SD + j]  = v;
            hb[(size_t)m*SD + j] = v16;
        }
    }
    __syncthreads();
    // iter-0 [A|B] from the embedded tile
    short8 aa0 = *(const short8*)(hs + l16*68 + quad*8);
    short8 aa1 = *(const short8*)(hs + l16*68 + 32 + quad*8);
    #pragma unroll
    for (int s = 0; s < 2; ++s) {
        int ncol = (jt + 4*s)*16 + l16;
        const short8* bp = (const short8*)(WabT + (size_t)ncol*SD + quad*8);
        floatx4 dd = __builtin_amdgcn_mfma_f32_16x16x32_bf16(aa0, bp[0], z4, 0, 0, 0);
        dd = __builtin_amdgcn_mfma_f32_16x16x32_bf16(aa1, bp[4], dd, 0, 0, 0);
        float bias2 = (s == 0) ? b_msg[ncol] : 0.f;
        int jc = jt*16 + l16;
        #pragma unroll
        for (int r = 0; r < 4; ++r) {
            int m = m0 + quad*4 + r;
            if (m >= n_nodes) break;
            float v = dd[r] + bias2;
            if (s == 0) Ab[(size_t)m*SD + jc] = f2bf(v);
            else        Bb[(size_t)m*SD + jc] = f2bf(v);
        }
    }
}

// One full MPNN iteration per launch. Block = 16-node tile, 4 waves.
// Phase 1 (agg): wave w aggregates nodes m0+w*4..+4, pair-interleaved edge chunks
//   -> m tile in LDS (bf16) + m_acc carry (fp32, global).
// Phase 2 (GRU): GI = m@W_i (A-frags from LDS), GH = hbr@W_h, gates, hnew -> h/hbw/LDS.
// Phase 3 (DO_AB): next iteration's [A|B] from the hnew LDS tile (ping-pong Ab/Bb).
template<int FIRST, int DO_AB>
__global__ __launch_bounds__(256) void mpnn_iter_kernel(
        float* __restrict__ h, const unsigned short* __restrict__ hbr,
        unsigned short* __restrict__ hbw,
        const unsigned short* __restrict__ Abr, const unsigned short* __restrict__ Bbr,
        unsigned short* __restrict__ Abw, unsigned short* __restrict__ Bbw,
        const unsigned short* __restrict__ Cp, const int* __restrict__ src_csr,
        const int* __restrict__ row_ptr, const int* __restrict__ deg,
        float* __restrict__ m_acc,
        const unsigned short* __restrict__ WiT, const unsigned short* __restrict__ WhT,
        const float* __restrict__ b_i, const float* __restrict__ b_h,
        const unsigned short* __restrict__ WabT, const float* __restrict__ b_msg,
        int n_nodes, int Lcap) {
    __shared__ unsigned short hsm[16 * 68];   // m tile (bf16)
    __shared__ unsigned short hsn[16 * 68];   // hnew tile (bf16)
    int w = threadIdx.x >> 6, lane = threadIdx.x & 63;
    int m0 = blockIdx.x * 16;
    if (m0 >= n_nodes) return;

    // ---- Phase 1: aggregation, 4 nodes per wave ----
    int e0[4], dg[4]; float aval[4], base[4];
    #pragma unroll
    for (int u = 0; u < 4; ++u) {
        int n = m0 + w*4 + u;
        bool v = n < n_nodes;
        int nc = v ? n : n_nodes - 1;
        e0[u] = row_ptr[nc];
        dg[u] = v ? deg[nc] : 0;
        aval[u] = bf2f(Abr[(size_t)nc*SD + lane]);
        base[u] = FIRST ? 0.f : m_acc[(size_t)nc*SD + lane];
    }
    float acc[4] = {0.f, 0.f, 0.f, 0.f};
    int mx = max(max(dg[0], dg[1]), max(dg[2], dg[3]));
    for (int c = 0; c*16 < mx; ++c) {
        #pragma unroll
        for (int up = 0; up < 2; ++up) {           // node pairs: 32 gathers + 16 C-loads in flight
            int sv[2]; unsigned cp2[2][8]; float bv[2][16];
            #pragma unroll
            for (int q = 0; q < 2; ++q) {
                int u = up*2 + q;
                int ilast = e0[u] + (dg[u] > 0 ? dg[u] - 1 : 0);
                int i = e0[u] + c*16 + (lane & 15);
                if (i > ilast) i = ilast;
                sv[q] = src_csr[i];
                int pb = (e0[u] >> 1) + c*8;
                #pragma unroll
                for (int t2 = 0; t2 < 8; ++t2) {
                    int pi = pb + t2; if (pi > Lcap) pi = Lcap;
                    cp2[q][t2] = *(const unsigned*)(Cp + (size_t)pi*128 + lane*2);
                }
            }
            #pragma unroll
            for (int q = 0; q < 2; ++q) {
                #pragma unroll
                for (int t = 0; t < 16; ++t) {
                    int s = __builtin_amdgcn_readlane(sv[q], t);
                    bv[q][t] = bf2f(Bbr[(size_t)s*SD + lane]);   // clamped src -> always valid
                }
            }
            #pragma unroll
            for (int q = 0; q < 2; ++q) {
                int u = up*2 + q;
                int cnt = dg[u] - c*16;
                #pragma unroll
                for (int t = 0; t < 16; ++t) {
                    if (t < cnt) {
                        float cv = bf2f((unsigned short)((t & 1) ? (cp2[q][t>>1] >> 16)
                                                                 : (cp2[q][t>>1] & 0xFFFF)));
                        acc[u] += fmaxf(aval[u] + bv[q][t] + cv, 0.f);
                    }
                }
            }
        }
    }
    #pragma unroll
    for (int u = 0; u < 4; ++u) {
        int n = m0 + w*4 + u;
        float nv = base[u] + acc[u];
        hsm[(w*4 + u)*68 + lane] = f2bf(nv);
        if (n < n_nodes) m_acc[(size_t)n*SD + lane] = nv;
    }
    __syncthreads();

    // ---- Phase 2: GRU via MFMA (m frags from LDS) ----
    int quad = lane >> 4, l16 = lane & 15;
    int mrow = m0 + l16; if (mrow >= n_nodes) mrow = n_nodes - 1;
    const short8* hp = (const short8*)(hbr + (size_t)mrow*SD + quad*8);
    short8 ha0 = hp[0], ha1 = hp[4];
    short8 ma0 = *(const short8*)(hsm + l16*68 + quad*8);
    short8 ma1 = *(const short8*)(hsm + l16*68 + 32 + quad*8);
    int j0 = w * 16;
    floatx4 di[3], dh[3];
    floatx4 z4 = {0.f,0.f,0.f,0.f};
    #pragma unroll
    for (int g = 0; g < 3; ++g) {
        int n = g*64 + j0 + l16;
        const short8* bi = (const short8*)(WiT + (size_t)n*SD + quad*8);
        const short8* bh = (const short8*)(WhT + (size_t)n*SD + quad*8);
        di[g] = __builtin_amdgcn_mfma_f32_16x16x32_bf16(ma0, bi[0], z4,    0, 0, 0);
        di[g] = __builtin_amdgcn_mfma_f32_16x16x32_bf16(ma1, bi[4], di[g], 0, 0, 0);
        dh[g] = __builtin_amdgcn_mfma_f32_16x16x32_bf16(ha0, bh[0], z4,    0, 0, 0);
        dh[g] = __builtin_amdgcn_mfma_f32_16x16x32_bf16(ha1, bh[4], dh[g], 0, 0, 0);
    }
    int j = j0 + l16;
    float bir = b_i[j], biz = b_i[64+j], bin = b_i[128+j];
    float bhr = b_h[j], bhz = b_h[64+j], bhn = b_h[128+j];
    #pragma unroll
    for (int r = 0; r < 4; ++r) {
        int m = m0 + quad*4 + r;
        int mc = m < n_nodes ? m : n_nodes - 1;
        float rg = sigmoid_f(di[0][r] + bir + dh[0][r] + bhr);
        float zg = sigmoid_f(di[1][r] + biz + dh[1][r] + bhz);
        float ng = tanh_f(di[2][r] + bin + rg * (dh[2][r] + bhn));
        float hold = h[(size_t)mc*SD + j];
        float hnew = (1.f - zg) * ng + zg * hold;
        unsigned short hb16 = f2bf(hnew);
        hsn[(quad*4 + r)*68 + j] = hb16;
        if (m < n_nodes) {
            h[(size_t)m*SD + j]   = hnew;
            hbw[(size_t)m*SD + j] = hb16;
        }
    }

    // ---- Phase 3: next iteration's [A|B] ----
    if (DO_AB) {
        __syncthreads();
        short8 a0 = *(const short8*)(hsn + l16*68 + quad*8);
        short8 a1 = *(const short8*)(hsn + l16*68 + 32 + quad*8);
        #pragma unroll
        for (int s = 0; s < 2; ++s) {
            int ncol = (w + 4*s)*16 + l16;
            const short8* bp = (const short8*)(WabT + (size_t)ncol*SD + quad*8);
            floatx4 d = __builtin_amdgcn_mfma_f32_16x16x32_bf16(a0, bp[0], z4, 0, 0, 0);
            d = __builtin_amdgcn_mfma_f32_16x16x32_bf16(a1, bp[4], d, 0, 0, 0);
            float bias = (s == 0) ? b_msg[ncol] : 0.f;
            int jc = w*16 + l16;
            #pragma unroll
            for (int r = 0; r < 4; ++r) {
                int m = m0 + quad*4 + r;
                if (m >= n_nodes) break;
                float v = d[r] + bias;
                if (s == 0) Abw[(size_t)m*SD + jc] = f2bf(v);
                else        Bbw[(size_t)m*SD + jc] = f2bf(v);
            }
        }
    }
}

// Readout: LDS-staged 128-node tile, thread-per-node MLP, shuffle-reduce, 32 atomics/block.
__global__ __launch_bounds__(128) void readout_kernel(
        const float* __restrict__ h, const float* __restrict__ W_r1, const float* __restrict__ b_r1,
        const float* __restrict__ W_r2, const float* __restrict__ b_r2,
        float* __restrict__ out, int n_nodes) {
    __shared__ float hsr[128 * 65];
    __shared__ float osum[2 * RD];
    int tile0 = blockIdx.x * 128;
    #pragma unroll
    for (int j = 0; j < 16; ++j) {
        int f = threadIdx.x + j * 128;
        int row = f >> 4, c4 = (f & 15) * 4;
        int n = tile0 + row;
        float4 v = make_float4(0.f, 0.f, 0.f, 0.f);
        if (n < n_nodes) v = ((const float4*)(h + (size_t)n * SD))[f & 15];
        hsr[row*65 + c4 + 0] = v.x;
        hsr[row*65 + c4 + 1] = v.y;
        hsr[row*65 + c4 + 2] = v.z;
        hsr[row*65 + c4 + 3] = v.w;
    }
    __syncthreads();
    float o[RD];
    #pragma unroll
    for (int c = 0; c < RD; ++c) o[c] = 0.f;
    int n = tile0 + threadIdx.x;
    if (n < n_nodes) {
        const float* hr = hsr + threadIdx.x * 65;
        float t[RH];
        #pragma unroll
        for (int i = 0; i < RH; ++i) t[i] = b_r1[i];
        #pragma unroll 4
        for (int k = 0; k < SD; ++k) {
            float hv = hr[k];
            #pragma unroll
            for (int i = 0; i < RH; ++i) t[i] += hv * W_r1[k*RH + i];
        }
        #pragma unroll
        for (int i = 0; i < RH; ++i) t[i] = fmaxf(t[i], 0.f);
        #pragma unroll
        for (int c = 0; c < RD; ++c) {
            float s = b_r2[c];
            #pragma unroll
            for (int i = 0; i < RH; ++i) s += t[i] * W_r2[i*RD + c];
            o[c] = s;
        }
    }
    int lane = threadIdx.x & 63;
    int wv = threadIdx.x >> 6;
    #pragma unroll
    for (int c = 0; c < RD; ++c) {
        float v = o[c];
        for (int off = 32; off > 0; off >>= 1) v += __shfl_down(v, off);
        if (lane == 0) osum[wv*RD + c] = v;
    }
    __syncthreads();
    if (threadIdx.x < RD) atomicAdd(&out[threadIdx.x], osum[threadIdx.x] + osum[RD + threadIdx.x]);
}

extern "C" void kernel_launch(void* const* d_in, const int* in_sizes, int n_in,
                              void* d_out, int out_size, void* d_ws, size_t ws_size,
                              hipStream_t stream) {
    const float* node_data = (const float*)d_in[0];
    const float* edge_data = (const float*)d_in[1];
    const int*   edge_src  = (const int*)d_in[2];
    const int*   edge_dst  = (const int*)d_in[3];
    const float* W_embed   = (const float*)d_in[4];
    const float* b_embed   = (const float*)d_in[5];
    const float* W_msg     = (const float*)d_in[6];
    const float* b_msg     = (const float*)d_in[7];
    const float* W_i       = (const float*)d_in[8];
    const float* b_i       = (const float*)d_in[9];
    const float* W_h       = (const float*)d_in[10];
    const float* b_h       = (const float*)d_in[11];
    const float* W_r1      = (const float*)d_in[12];
    const float* b_r1      = (const float*)d_in[13];
    const float* W_r2      = (const float*)d_in[14];
    const float* b_r2      = (const float*)d_in[15];

    int n_nodes = in_sizes[0] / VD;    // 20000
    int n_edges = in_sizes[2];         // 320000
    int Lmax = n_edges + n_nodes + 64; // padded CSR capacity

    char* ws = (char*)d_ws;
    size_t off = 0;
    auto alloc = [&](size_t bytes) {
        void* p = ws + off;
        off = (off + bytes + 255) & ~(size_t)255;
        return p;
    };
    float* h            = (float*)alloc((size_t)n_nodes * SD * sizeof(float));
    float* m_acc        = (float*)alloc((size_t)n_nodes * SD * sizeof(float));
    unsigned short* hbA = (unsigned short*)alloc((size_t)n_nodes * SD * 2);
    unsigned short* hbB = (unsigned short*)alloc((size_t)n_nodes * SD * 2);
    unsigned short* Ab0 = (unsigned short*)alloc((size_t)n_nodes * SD * 2);
    unsigned short* Bb0 = (unsigned short*)alloc((size_t)n_nodes * SD * 2);
    unsigned short* Ab1 = (unsigned short*)alloc((size_t)n_nodes * SD * 2);
    unsigned short* Bb1 = (unsigned short*)alloc((size_t)n_nodes * SD * 2);
    unsigned short* Cp  = (unsigned short*)alloc((size_t)(Lmax + 32) * SD * 2);
    int*   src_csr      = (int*)alloc((size_t)(Lmax + 32) * sizeof(int));
    int*   row_ptr      = (int*)alloc((size_t)(n_nodes + 1) * sizeof(int));
    // contiguous zero-init region: deg, fillc, eid (one memset)
    char*  zbase        = (char*)alloc(0);
    int*   deg          = (int*)alloc((size_t)n_nodes * sizeof(int));
    int*   fillc        = (int*)alloc((size_t)n_nodes * sizeof(int));
    int*   eid          = (int*)alloc((size_t)(Lmax + 32) * sizeof(int));
    char*  zend         = (char*)alloc(0);
    unsigned short* WabT = (unsigned short*)alloc(128*64*2);
    unsigned short* WiT  = (unsigned short*)alloc(192*64*2);
    unsigned short* WhT  = (unsigned short*)alloc(192*64*2);
    unsigned short* W3T  = (unsigned short*)alloc(64*32*2);
    unsigned short* WeT  = (unsigned short*)alloc(64*32*2);
    (void)ws_size; (void)n_in;

    hipMemsetAsync(zbase, 0, (size_t)(zend - zbase), stream);
    hipMemsetAsync(d_out, 0, (size_t)out_size * sizeof(float), stream);

    prep_w_kernel<<<(128*64 + 192*64 + 64*32 + 64*32 + 255)/256, 256, 0, stream>>>(
        W_msg, W_i, W_h, W_embed, WabT, WiT, WhT, W3T, WeT);

    hist_kernel<<<(n_edges + 255)/256, 256, 0, stream>>>(edge_dst, deg, n_edges);
    scan_kernel<<<1, 1024, 0, stream>>>(deg, row_ptr, n_nodes);
    fill_kernel<<<(n_edges + 255)/256, 256, 0, stream>>>(edge_dst, row_ptr, fillc, eid, n_edges);

    int ec_waves = (Lmax + 15) / 16;
    edgeconst_kernel<<<(ec_waves + 3)/4, 256, 0, stream>>>(eid, edge_src, edge_data, W3T,
                                                           src_csr, Cp, Lmax);

    int mtiles = (n_nodes + 15) / 16;
    embed_fused_kernel<<<mtiles, 256, 0, stream>>>(node_data, WeT, b_embed, h, hbA,
                                                   WabT, b_msg, Ab0, Bb0, n_nodes);

    int Lcap = (Lmax >> 1) - 1;
    // it0: read Ab0/Bb0, hbA -> hbB, write Ab1/Bb1
    mpnn_iter_kernel<1,1><<<mtiles, 256, 0, stream>>>(h, hbA, hbB, Ab0, Bb0, Ab1, Bb1,
        Cp, src_csr, row_ptr, deg, m_acc, WiT, WhT, b_i, b_h, WabT, b_msg, n_nodes, Lcap);
    // it1: read Ab1/Bb1, hbB -> hbA, write Ab0/Bb0
    mpnn_iter_kernel<0,1><<<mtiles, 256, 0, stream>>>(h, hbB, hbA, Ab1, Bb1, Ab0, Bb0,
        Cp, src_csr, row_ptr, deg, m_acc, WiT, WhT, b_i, b_h, WabT, b_msg, n_nodes, Lcap);
    // it2: read Ab0/Bb0, hbA -> hbB, no AB
    mpnn_iter_kernel<0,0><<<mtiles, 256, 0, stream>>>(h, hbA, hbB, Ab0, Bb0, Ab1, Bb1,
        Cp, src_csr, row_ptr, deg, m_acc, WiT, WhT, b_i, b_h, WabT, b_msg, n_nodes, Lcap);

    readout_kernel<<<(n_nodes + 127)/128, 128, 0, stream>>>(h, W_r1, b_r1, W_r2, b_r2,
                                                            (float*)d_out, n_nodes);
}

// Round 8
// 299.536 us; speedup vs baseline: 3.1158x; 1.0309x over previous
//
#include <hip/hip_runtime.h>

static constexpr int VD = 16;     // vertex feature dim
static constexpr int SD = 64;     // state dim
static constexpr int ED = 16;     // edge feature dim
static constexpr int RH = 10, RD = 32;
static constexpr int N_ITERS = 3;

typedef __attribute__((ext_vector_type(8))) short short8;
typedef __attribute__((ext_vector_type(4))) float floatx4;

__device__ __forceinline__ float sigmoid_f(float x) {
    return 1.f / (1.f + __expf(-x));
}
__device__ __forceinline__ float tanh_f(float x) {
    x = fminf(fmaxf(x, -20.f), 20.f);
    float e = __expf(2.f * x);
    return (e - 1.f) / (e + 1.f);
}
__device__ __forceinline__ unsigned short f2bf(float x) {   // round-to-nearest-even
    unsigned u = __float_as_uint(x);
    unsigned r = (u + 0x7FFFu + ((u >> 16) & 1u)) >> 16;
    return (unsigned short)r;
}
__device__ __forceinline__ float bf2f(unsigned short s) {
    return __uint_as_float(((unsigned)s) << 16);
}

// One-time bf16 weight transposes for MFMA B-operands ([n][k] layout).
__global__ void prep_w_kernel(const float* __restrict__ W_msg,
                              const float* __restrict__ W_i, const float* __restrict__ W_h,
                              const float* __restrict__ W_embed,
                              unsigned short* __restrict__ WabT, unsigned short* __restrict__ WiT,
                              unsigned short* __restrict__ WhT, unsigned short* __restrict__ W3T,
                              unsigned short* __restrict__ WeT) {
    int i = blockIdx.x * blockDim.x + threadIdx.x;
    if (i < 128*64) {                       // WabT[n][k]: n<64 -> W1 col n; else W2 col n-64
        int n = i >> 6, k = i & 63;
        WabT[i] = f2bf(W_msg[((n < 64 ? 0 : 64) + k)*64 + (n & 63)]);
    }
    int j = i - 128*64;
    if (j >= 0 && j < 192*64) {             // WiT/WhT[n][k] = W[k][n]
        int n = j >> 6, k = j & 63;
        WiT[j] = f2bf(W_i[k*192 + n]);
        WhT[j] = f2bf(W_h[k*192 + n]);
    }
    int l = i - 128*64 - 192*64;
    if (l >= 0 && l < 64*32) {              // W3T[n][k], k padded 16->32 with zeros
        int n = l >> 5, k = l & 31;
        W3T[l] = (k < 16) ? f2bf(W_msg[(128+k)*64 + n]) : (unsigned short)0;
    }
    int m = i - 128*64 - 192*64 - 64*32;
    if (m >= 0 && m < 64*32) {              // WeT[n][k], k padded 16->32 (embed)
        int n = m >> 5, k = m & 31;
        WeT[m] = (k < 16) ? f2bf(W_embed[k*64 + n]) : (unsigned short)0;
    }
}

__global__ void hist_kernel(const int* __restrict__ edge_dst, int* __restrict__ deg, int n_edges) {
    for (int e = blockIdx.x*blockDim.x + threadIdx.x; e < n_edges; e += gridDim.x*blockDim.x)
        atomicAdd(&deg[edge_dst[e]], 1);
}

// Exclusive scan of EVEN-PADDED degrees -> row_ptr. Shuffle-based: 2 barriers total.
__global__ __launch_bounds__(1024) void scan_kernel(const int* __restrict__ deg,
                                                    int* __restrict__ row_ptr,
                                                    int n_nodes) {
    __shared__ int wsum[16];
    int lid = threadIdx.x, lane = lid & 63, wv = lid >> 6;
    int C = (n_nodes + 1023) >> 10;
    int start = lid * C;
    int lsum = 0;
    for (int i = 0; i < C; ++i) {
        int idx = start + i;
        if (idx < n_nodes) lsum += (deg[idx] + 1) & ~1;
    }
    int x = lsum;                              // wave inclusive scan
    #pragma unroll
    for (int off = 1; off < 64; off <<= 1) {
        int y = __shfl_up(x, off);
        if (lane >= off) x += y;
    }
    if (lane == 63) wsum[wv] = x;
    __syncthreads();
    if (wv == 0 && lane < 16) {
        int t = wsum[lane];
        #pragma unroll
        for (int off = 1; off < 16; off <<= 1) {
            int y = __shfl_up(t, off);
            if (lane >= off) t += y;
        }
        wsum[lane] = t;
    }
    __syncthreads();
    int wbase = (wv > 0) ? wsum[wv - 1] : 0;
    int run = wbase + x - lsum;                // exclusive prefix for this thread
    for (int i = 0; i < C; ++i) {
        int idx = start + i;
        if (idx < n_nodes) { row_ptr[idx] = run; run += (deg[idx] + 1) & ~1; }
    }
}

__global__ void fill_kernel(const int* __restrict__ edge_dst, const int* __restrict__ row_ptr,
                            int* __restrict__ fillc, int* __restrict__ eid, int n_edges) {
    for (int e = blockIdx.x*blockDim.x + threadIdx.x; e < n_edges; e += gridDim.x*blockDim.x) {
        int d = edge_dst[e];
        int ofs = atomicAdd(&fillc[d], 1);
        eid[row_ptr[d] + ofs] = e;
    }
}

// Once: Cp[pair][col] (uint: lo=even edge, hi=odd edge) = edge_data@W3 (bf16) + src_csr gather.
// One wave per 16-position tile. Pair partner e^1 is in the SAME lane (regs r, r+1) ->
// pack one dense 4-byte store per pair (perfect coalescing, half the store count).
__global__ __launch_bounds__(256) void edgeconst_kernel(
        const int* __restrict__ eid, const int* __restrict__ edge_src,
        const float* __restrict__ edge_data, const unsigned short* __restrict__ W3T,
        int* __restrict__ src_csr, unsigned short* __restrict__ Cp, int Lmax) {
    int w = blockIdx.x * 4 + (threadIdx.x >> 6);
    int lane = threadIdx.x & 63;
    int e0 = w * 16;
    if (e0 >= Lmax) return;
    int quad = lane >> 4, l16 = lane & 15;
    int erow = e0 + l16;
    int ev = eid[erow];                      // coalesced; 0 for pads
    if (quad == 0) src_csr[erow] = edge_src[ev];
    short8 a0 = {0,0,0,0,0,0,0,0};           // k = quad*8..+8; real only k<16
    if (quad < 2) {
        const float4* ep = (const float4*)(edge_data + (size_t)ev*ED + quad*8);
        float4 x0 = ep[0], x1 = ep[1];
        a0[0]=(short)f2bf(x0.x); a0[1]=(short)f2bf(x0.y); a0[2]=(short)f2bf(x0.z); a0[3]=(short)f2bf(x0.w);
        a0[4]=(short)f2bf(x1.x); a0[5]=(short)f2bf(x1.y); a0[6]=(short)f2bf(x1.z); a0[7]=(short)f2bf(x1.w);
    }
    floatx4 z4 = {0.f,0.f,0.f,0.f};
    #pragma unroll
    for (int nt = 0; nt < 4; ++nt) {
        int n = nt*16 + l16;
        short8 b0 = *(const short8*)(W3T + (size_t)n*32 + quad*8);
        floatx4 d = __builtin_amdgcn_mfma_f32_16x16x32_bf16(a0, b0, z4, 0, 0, 0);
        #pragma unroll
        for (int rp = 0; rp < 2; ++rp) {     // pair (e, e+1), e = e0+quad*4+2rp (even)
            int e = e0 + quad*4 + 2*rp;
            unsigned pack = (unsigned)f2bf(d[2*rp]) | ((unsigned)f2bf(d[2*rp+1]) << 16);
            *(unsigned*)(Cp + (size_t)(e >> 1)*128 + n*2) = pack;
        }
    }
}

// Embed via MFMA (K=16 padded to 32) + fused iter-0 [A|B]. Block = 16-node tile, 4 waves.
__global__ __launch_bounds__(256) void embed_fused_kernel(
        const float* __restrict__ node_data, const unsigned short* __restrict__ WeT,
        const float* __restrict__ b_embed,
        unsigned short* __restrict__ hb,
        const unsigned short* __restrict__ WabT, const float* __restrict__ b_msg,
        unsigned short* __restrict__ Ab, unsigned short* __restrict__ Bb, int n_nodes) {
    __shared__ unsigned short hs[16 * 68];
    int jt = threadIdx.x >> 6, lane = threadIdx.x & 63;
    int m0 = blockIdx.x * 16;
    if (m0 >= n_nodes) return;
    int quad = lane >> 4, l16 = lane & 15;
    int mrow = m0 + l16; if (mrow >= n_nodes) mrow = n_nodes - 1;
    short8 a0 = {0,0,0,0,0,0,0,0};
    if (quad < 2) {
        const float4* np = (const float4*)(node_data + (size_t)mrow*VD + quad*8);
        float4 x0 = np[0], x1 = np[1];
        a0[0]=(short)f2bf(x0.x); a0[1]=(short)f2bf(x0.y); a0[2]=(short)f2bf(x0.z); a0[3]=(short)f2bf(x0.w);
        a0[4]=(short)f2bf(x1.x); a0[5]=(short)f2bf(x1.y); a0[6]=(short)f2bf(x1.z); a0[7]=(short)f2bf(x1.w);
    }
    int j = jt*16 + l16;
    short8 b0 = *(const short8*)(WeT + (size_t)j*32 + quad*8);
    floatx4 z4 = {0.f,0.f,0.f,0.f};
    floatx4 d = __builtin_amdgcn_mfma_f32_16x16x32_bf16(a0, b0, z4, 0, 0, 0);
    float bias = b_embed[j];
    #pragma unroll
    for (int r = 0; r < 4; ++r) {
        int m = m0 + quad*4 + r;
        unsigned short v16 = f2bf(d[r] + bias);
        hs[(quad*4 + r)*68 + j] = v16;
        if (m < n_nodes) hb[(size_t)m*SD + j] = v16;
    }
    __syncthreads();
    short8 aa0 = *(const short8*)(hs + l16*68 + quad*8);
    short8 aa1 = *(const short8*)(hs + l16*68 + 32 + quad*8);
    #pragma unroll
    for (int s = 0; s < 2; ++s) {
        int ncol = (jt + 4*s)*16 + l16;
        const short8* bp = (const short8*)(WabT + (size_t)ncol*SD + quad*8);
        floatx4 dd = __builtin_amdgcn_mfma_f32_16x16x32_bf16(aa0, bp[0], z4, 0, 0, 0);
        dd = __builtin_amdgcn_mfma_f32_16x16x32_bf16(aa1, bp[4], dd, 0, 0, 0);
        float bias2 = (s == 0) ? b_msg[ncol] : 0.f;
        int jc = jt*16 + l16;
        #pragma unroll
        for (int r = 0; r < 4; ++r) {
            int m = m0 + quad*4 + r;
            if (m >= n_nodes) break;
            float v = dd[r] + bias2;
            if (s == 0) Ab[(size_t)m*SD + jc] = f2bf(v);
            else        Bb[(size_t)m*SD + jc] = f2bf(v);
        }
    }
}

// One full MPNN iteration. Block = 16-node tile, 4 waves.
// Phase 1 (agg): pair-interleaved edge chunks -> m tile in LDS (bf16) + bf16 m carry.
// Phase 2 (GRU): GI = m@W_i (LDS frags), GH = hbr@W_h, gates, hnew -> hbw + LDS.
// Phase 3: !LAST -> next [A|B] from hnew LDS tile; LAST -> fused readout partials.
template<int FIRST, int LAST>
__global__ __launch_bounds__(256) void mpnn_iter_kernel(
        const unsigned short* __restrict__ hbr, unsigned short* __restrict__ hbw,
        const unsigned short* __restrict__ Abr, const unsigned short* __restrict__ Bbr,
        unsigned short* __restrict__ Abw, unsigned short* __restrict__ Bbw,
        const unsigned short* __restrict__ Cp, const int* __restrict__ src_csr,
        const int* __restrict__ row_ptr, const int* __restrict__ deg,
        unsigned short* __restrict__ m_accb,
        const unsigned short* __restrict__ WiT, const unsigned short* __restrict__ WhT,
        const float* __restrict__ b_i, const float* __restrict__ b_h,
        const unsigned short* __restrict__ WabT, const float* __restrict__ b_msg,
        const float* __restrict__ W_r1, const float* __restrict__ b_r1,
        const float* __restrict__ W_r2, float* __restrict__ partials,
        int n_nodes, int Lcap) {
    __shared__ unsigned short hsm[16 * 68];   // m tile (bf16)
    __shared__ unsigned short hsn[16 * 68];   // hnew tile (bf16)
    int w = threadIdx.x >> 6, lane = threadIdx.x & 63;
    int m0 = blockIdx.x * 16;
    if (m0 >= n_nodes) return;

    // ---- Phase 1: aggregation, 4 nodes per wave ----
    int e0[4], dg[4]; float aval[4], base[4];
    #pragma unroll
    for (int u = 0; u < 4; ++u) {
        int n = m0 + w*4 + u;
        bool v = n < n_nodes;
        int nc = v ? n : n_nodes - 1;
        e0[u] = row_ptr[nc];
        dg[u] = v ? deg[nc] : 0;
        aval[u] = bf2f(Abr[(size_t)nc*SD + lane]);
        base[u] = FIRST ? 0.f : bf2f(m_accb[(size_t)nc*SD + lane]);
    }
    float acc[4] = {0.f, 0.f, 0.f, 0.f};
    int mx = max(max(dg[0], dg[1]), max(dg[2], dg[3]));
    for (int c = 0; c*16 < mx; ++c) {
        #pragma unroll
        for (int up = 0; up < 2; ++up) {
            int sv[2]; unsigned cp2[2][8]; float bv[2][16];
            #pragma unroll
            for (int q = 0; q < 2; ++q) {
                int u = up*2 + q;
                int ilast = e0[u] + (dg[u] > 0 ? dg[u] - 1 : 0);
                int i = e0[u] + c*16 + (lane & 15);
                if (i > ilast) i = ilast;
                sv[q] = src_csr[i];
                int pb = (e0[u] >> 1) + c*8;
                #pragma unroll
                for (int t2 = 0; t2 < 8; ++t2) {
                    int pi = pb + t2; if (pi > Lcap) pi = Lcap;
                    cp2[q][t2] = *(const unsigned*)(Cp + (size_t)pi*128 + lane*2);
                }
            }
            #pragma unroll
            for (int q = 0; q < 2; ++q) {
                #pragma unroll
                for (int t = 0; t < 16; ++t) {
                    int s = __builtin_amdgcn_readlane(sv[q], t);
                    bv[q][t] = bf2f(Bbr[(size_t)s*SD + lane]);
                }
            }
            #pragma unroll
            for (int q = 0; q < 2; ++q) {
                int u = up*2 + q;
                int cnt = dg[u] - c*16;
                #pragma unroll
                for (int t = 0; t < 16; ++t) {
                    if (t < cnt) {
                        float cv = bf2f((unsigned short)((t & 1) ? (cp2[q][t>>1] >> 16)
                                                                 : (cp2[q][t>>1] & 0xFFFF)));
                        acc[u] += fmaxf(aval[u] + bv[q][t] + cv, 0.f);
                    }
                }
            }
        }
    }
    #pragma unroll
    for (int u = 0; u < 4; ++u) {
        int n = m0 + w*4 + u;
        unsigned short nv16 = f2bf(base[u] + acc[u]);
        hsm[(w*4 + u)*68 + lane] = nv16;
        if (!LAST && n < n_nodes) m_accb[(size_t)n*SD + lane] = nv16;
    }
    __syncthreads();

    // ---- Phase 2: GRU via MFMA ----
    int quad = lane >> 4, l16 = lane & 15;
    int mrow = m0 + l16; if (mrow >= n_nodes) mrow = n_nodes - 1;
    const short8* hp = (const short8*)(hbr + (size_t)mrow*SD + quad*8);
    short8 ha0 = hp[0], ha1 = hp[4];
    short8 ma0 = *(const short8*)(hsm + l16*68 + quad*8);
    short8 ma1 = *(const short8*)(hsm + l16*68 + 32 + quad*8);
    int j0 = w * 16;
    floatx4 di[3], dh[3];
    floatx4 z4 = {0.f,0.f,0.f,0.f};
    #pragma unroll
    for (int g = 0; g < 3; ++g) {
        int n = g*64 + j0 + l16;
        const short8* bi = (const short8*)(WiT + (size_t)n*SD + quad*8);
        const short8* bh = (const short8*)(WhT + (size_t)n*SD + quad*8);
        di[g] = __builtin_amdgcn_mfma_f32_16x16x32_bf16(ma0, bi[0], z4,    0, 0, 0);
        di[g] = __builtin_amdgcn_mfma_f32_16x16x32_bf16(ma1, bi[4], di[g], 0, 0, 0);
        dh[g] = __builtin_amdgcn_mfma_f32_16x16x32_bf16(ha0, bh[0], z4,    0, 0, 0);
        dh[g] = __builtin_amdgcn_mfma_f32_16x16x32_bf16(ha1, bh[4], dh[g], 0, 0, 0);
    }
    int j = j0 + l16;
    float bir = b_i[j], biz = b_i[64+j], bin = b_i[128+j];
    float bhr = b_h[j], bhz = b_h[64+j], bhn = b_h[128+j];
    #pragma unroll
    for (int r = 0; r < 4; ++r) {
        int m = m0 + quad*4 + r;
        int mc = m < n_nodes ? m : n_nodes - 1;
        float rg = sigmoid_f(di[0][r] + bir + dh[0][r] + bhr);
        float zg = sigmoid_f(di[1][r] + biz + dh[1][r] + bhz);
        float ng = tanh_f(di[2][r] + bin + rg * (dh[2][r] + bhn));
        float hold = bf2f(hbr[(size_t)mc*SD + j]);     // bf16 carry (no fp32 h)
        float hnew = (1.f - zg) * ng + zg * hold;
        unsigned short hb16 = f2bf(hnew);
        hsn[(quad*4 + r)*68 + j] = hb16;
        if (!LAST && m < n_nodes) hbw[(size_t)m*SD + j] = hb16;
    }

    if (!LAST) {
        // ---- Phase 3a: next iteration's [A|B] ----
        __syncthreads();
        short8 a0 = *(const short8*)(hsn + l16*68 + quad*8);
        short8 a1 = *(const short8*)(hsn + l16*68 + 32 + quad*8);
        #pragma unroll
        for (int s = 0; s < 2; ++s) {
            int ncol = (w + 4*s)*16 + l16;
            const short8* bp = (const short8*)(WabT + (size_t)ncol*SD + quad*8);
            floatx4 d = __builtin_amdgcn_mfma_f32_16x16x32_bf16(a0, bp[0], z4, 0, 0, 0);
            d = __builtin_amdgcn_mfma_f32_16x16x32_bf16(a1, bp[4], d, 0, 0, 0);
            float bias = (s == 0) ? b_msg[ncol] : 0.f;
            int jc = w*16 + l16;
            #pragma unroll
            for (int r = 0; r < 4; ++r) {
                int m = m0 + quad*4 + r;
                if (m >= n_nodes) break;
                float v = d[r] + bias;
                if (s == 0) Abw[(size_t)m*SD + jc] = f2bf(v);
                else        Bbw[(size_t)m*SD + jc] = f2bf(v);
            }
        }
    } else {
        // ---- Phase 3b: fused readout partials (per-block 32 floats, no atomics) ----
        __syncthreads();
        __shared__ float ts[16 * 12];        // hidden, padded stride
        __shared__ float po[512];
        int tid = threadIdx.x;
        if (tid < 16 * RH) {
            int node = tid / RH, i = tid - node * RH;
            float a = b_r1[i];
            #pragma unroll 8
            for (int k = 0; k < SD; ++k)
                a += bf2f(hsn[node*68 + k]) * W_r1[k*RH + i];
            ts[node*12 + i] = fmaxf(a, 0.f);
        }
        __syncthreads();
        #pragma unroll
        for (int s = 0; s < 2; ++s) {
            int task = tid + s*256;          // (node, c)
            int node = task >> 5, c = task & 31;
            float v = 0.f;
            if (m0 + node < n_nodes) {
                #pragma unroll
                for (int i = 0; i < RH; ++i) v += ts[node*12 + i] * W_r2[i*RD + c];
            }
            po[task] = v;
        }
        __syncthreads();
        if (tid < RD) {
            float s2 = 0.f;
            #pragma unroll
            for (int n = 0; n < 16; ++n) s2 += po[n*32 + tid];
            partials[(size_t)blockIdx.x * RD + tid] = s2;
        }
    }
}

// Final: out[c] = sum over blocks of partials + n_nodes * b_r2[c]. One block.
__global__ __launch_bounds__(1024) void final_sum_kernel(
        const float* __restrict__ partials, const float* __restrict__ b_r2,
        float* __restrict__ out, int mtiles, int n_nodes) {
    __shared__ float red[1024];
    int c = threadIdx.x & 31, g = threadIdx.x >> 5;   // 32 groups x 32 cols
    float s = 0.f;
    for (int t = g; t < mtiles; t += 32) s += partials[(size_t)t*RD + c];
    red[threadIdx.x] = s;
    __syncthreads();
    #pragma unroll
    for (int off = 512; off >= 32; off >>= 1) {
        if ((int)threadIdx.x < off) red[threadIdx.x] += red[threadIdx.x + off];
        __syncthreads();
    }
    if (threadIdx.x < RD) out[threadIdx.x] = red[threadIdx.x] + (float)n_nodes * b_r2[threadIdx.x];
}

extern "C" void kernel_launch(void* const* d_in, const int* in_sizes, int n_in,
                              void* d_out, int out_size, void* d_ws, size_t ws_size,
                              hipStream_t stream) {
    const float* node_data = (const float*)d_in[0];
    const float* edge_data = (const float*)d_in[1];
    const int*   edge_src  = (const int*)d_in[2];
    const int*   edge_dst  = (const int*)d_in[3];
    const float* W_embed   = (const float*)d_in[4];
    const float* b_embed   = (const float*)d_in[5];
    const float* W_msg     = (const float*)d_in[6];
    const float* b_msg     = (const float*)d_in[7];
    const float* W_i       = (const float*)d_in[8];
    const float* b_i       = (const float*)d_in[9];
    const float* W_h       = (const float*)d_in[10];
    const float* b_h       = (const float*)d_in[11];
    const float* W_r1      = (const float*)d_in[12];
    const float* b_r1      = (const float*)d_in[13];
    const float* W_r2      = (const float*)d_in[14];
    const float* b_r2      = (const float*)d_in[15];

    int n_nodes = in_sizes[0] / VD;    // 20000
    int n_edges = in_sizes[2];         // 320000
    int Lmax = n_edges + n_nodes + 64; // padded CSR capacity
    int mtiles = (n_nodes + 15) / 16;

    char* ws = (char*)d_ws;
    size_t off = 0;
    auto alloc = [&](size_t bytes) {
        void* p = ws + off;
        off = (off + bytes + 255) & ~(size_t)255;
        return p;
    };
    unsigned short* m_accb = (unsigned short*)alloc((size_t)n_nodes * SD * 2);
    unsigned short* hbA = (unsigned short*)alloc((size_t)n_nodes * SD * 2);
    unsigned short* hbB = (unsigned short*)alloc((size_t)n_nodes * SD * 2);
    unsigned short* Ab0 = (unsigned short*)alloc((size_t)n_nodes * SD * 2);
    unsigned short* Bb0 = (unsigned short*)alloc((size_t)n_nodes * SD * 2);
    unsigned short* Ab1 = (unsigned short*)alloc((size_t)n_nodes * SD * 2);
    unsigned short* Bb1 = (unsigned short*)alloc((size_t)n_nodes * SD * 2);
    unsigned short* Cp  = (unsigned short*)alloc((size_t)(Lmax + 32) * SD * 2);
    int*   src_csr      = (int*)alloc((size_t)(Lmax + 32) * sizeof(int));
    int*   row_ptr      = (int*)alloc((size_t)(n_nodes + 1) * sizeof(int));
    float* partials     = (float*)alloc((size_t)mtiles * RD * sizeof(float));
    // contiguous zero-init region: deg, fillc, eid (one memset)
    char*  zbase        = (char*)alloc(0);
    int*   deg          = (int*)alloc((size_t)n_nodes * sizeof(int));
    int*   fillc        = (int*)alloc((size_t)n_nodes * sizeof(int));
    int*   eid          = (int*)alloc((size_t)(Lmax + 32) * sizeof(int));
    char*  zend         = (char*)alloc(0);
    unsigned short* WabT = (unsigned short*)alloc(128*64*2);
    unsigned short* WiT  = (unsigned short*)alloc(192*64*2);
    unsigned short* WhT  = (unsigned short*)alloc(192*64*2);
    unsigned short* W3T  = (unsigned short*)alloc(64*32*2);
    unsigned short* WeT  = (unsigned short*)alloc(64*32*2);
    (void)ws_size; (void)n_in;

    hipMemsetAsync(zbase, 0, (size_t)(zend - zbase), stream);

    prep_w_kernel<<<(128*64 + 192*64 + 64*32 + 64*32 + 255)/256, 256, 0, stream>>>(
        W_msg, W_i, W_h, W_embed, WabT, WiT, WhT, W3T, WeT);

    hist_kernel<<<(n_edges + 255)/256, 256, 0, stream>>>(edge_dst, deg, n_edges);
    scan_kernel<<<1, 1024, 0, stream>>>(deg, row_ptr, n_nodes);
    fill_kernel<<<(n_edges + 255)/256, 256, 0, stream>>>(edge_dst, row_ptr, fillc, eid, n_edges);

    int ec_waves = (Lmax + 15) / 16;
    edgeconst_kernel<<<(ec_waves + 3)/4, 256, 0, stream>>>(eid, edge_src, edge_data, W3T,
                                                           src_csr, Cp, Lmax);

    embed_fused_kernel<<<mtiles, 256, 0, stream>>>(node_data, WeT, b_embed, hbA,
                                                   WabT, b_msg, Ab0, Bb0, n_nodes);

    int Lcap = (Lmax >> 1) - 1;
    // it0: read Ab0/Bb0, hbA -> hbB, write Ab1/Bb1
    mpnn_iter_kernel<1,0><<<mtiles, 256, 0, stream>>>(hbA, hbB, Ab0, Bb0, Ab1, Bb1,
        Cp, src_csr, row_ptr, deg, m_accb, WiT, WhT, b_i, b_h, WabT, b_msg,
        W_r1, b_r1, W_r2, partials, n_nodes, Lcap);
    // it1: read Ab1/Bb1, hbB -> hbA, write Ab0/Bb0
    mpnn_iter_kernel<0,0><<<mtiles, 256, 0, stream>>>(hbB, hbA, Ab1, Bb1, Ab0, Bb0,
        Cp, src_csr, row_ptr, deg, m_accb, WiT, WhT, b_i, b_h, WabT, b_msg,
        W_r1, b_r1, W_r2, partials, n_nodes, Lcap);
    // it2 (LAST): read Ab0/Bb0, hbA; fused readout partials, no AB / m / hb writes
    mpnn_iter_kernel<0,1><<<mtiles, 256, 0, stream>>>(hbA, hbB, Ab0, Bb0, Ab1, Bb1,
        Cp, src_csr, row_ptr, deg, m_accb, WiT, WhT, b_i, b_h, WabT, b_msg,
        W_r1, b_r1, W_r2, partials, n_nodes, Lcap);

    final_sum_kernel<<<1, 1024, 0, stream>>>(partials, b_r2, (float*)d_out, mtiles, n_nodes);
}